// Round 9
// baseline (3978.131 us; speedup 1.0000x reference)
//
#include <hip/hip_runtime.h>
#include <math.h>

#define NBATCH 4
#define NBLK 512

typedef unsigned long long u64;

// branchless ascending compare-swap on u64 keys
#define CSWAP(a, b)                                          \
  {                                                          \
    u64 _mn = (b < a) ? b : a;                               \
    u64 _mx = (b < a) ? a : b;                               \
    a = _mn;                                                 \
    b = _mx;                                                 \
  }

struct PanP {
  const float* xyz;
  const float *W0, *b0, *A0, *W1, *b1, *A1, *W2, *b2, *A2, *W3, *b3, *A3;
  const float *W4, *b4, *A4, *W5, *b5, *A5, *W6, *b6, *A6;
  const float *Wq1, *Wk1, *Wv1, *Wq2, *Wk2, *Wv2, *Wq3, *Wk3, *Wv3, *Wf, *bf;
  float* out;
  float4 *xw0, *xw1, *xw2, *xw3;
  int *idxK0, *idxK1, *idxK2, *idxK3, *idx1, *idx2, *idx3;
  float *fea0, *fea1, *fea1b, *fea2a, *fea2b, *fea2c, *fea2d, *fea3a, *fea3b;
  float *qb, *kb, *vb;
  int *idxI0, *idxI1, *idxI2;
  float *wI0, *wI1, *wI2;
  float *Zb4, *Zb5, *Zb6, *Y4, *Y5, *Y6, *wfb;
  unsigned* bar;  // [0]=cnt [1]=gen, zeroed by hipMemsetAsync each call
  float r2_0, r2_1, r2_2, r2_3;
};

// ---------------------------------------------------------------------------
// Grid barrier: generation counter, agent-scope atomics + threadfence.
// Valid because grid (512 blocks, 33KB LDS, 256 thr) <= co-residency capacity.
// ---------------------------------------------------------------------------
__device__ __forceinline__ void gsync(unsigned* bar) {
  __syncthreads();
  if (threadIdx.x == 0) {
    __threadfence();
    unsigned old = __hip_atomic_fetch_add(&bar[0], 1u, __ATOMIC_ACQ_REL,
                                          __HIP_MEMORY_SCOPE_AGENT);
    unsigned mygen = old / NBLK + 1u;
    if (old % NBLK == (unsigned)(NBLK - 1)) {
      __hip_atomic_store(&bar[1], mygen, __ATOMIC_RELEASE, __HIP_MEMORY_SCOPE_AGENT);
    }
    while (__hip_atomic_load(&bar[1], __ATOMIC_ACQUIRE, __HIP_MEMORY_SCOPE_AGENT) < mygen) {
      __builtin_amdgcn_s_sleep(2);
    }
    __threadfence();
  }
  __syncthreads();
}

// ---------------------------------------------------------------------------
// kNN-16 top-16 search (per-wave) on packed float4 coords. Key =
// (d2_bits<<32)|idx == exact (d2, idx) lexicographic order == stable top_k.
// ---------------------------------------------------------------------------
__device__ __forceinline__ void knn16_search(const float4* __restrict__ xwb, int N, int n,
                                             int lane, u64* lists, u64* win) {
#pragma clang fp contract(off)
  float4 q = xwb[n];
  float qq = q.w;
  const u64 SENT = ((u64)0x7F800000u << 32) | (unsigned)lane;
  u64 k0 = SENT, k1 = SENT, k2 = SENT, k3 = SENT, k4 = SENT, k5 = SENT, k6 = SENT,
      k7 = SENT, k8 = SENT, k9 = SENT, k10 = SENT, k11 = SENT, k12 = SENT, k13 = SENT,
      k14 = SENT, k15 = SENT;
  int rounds = N >> 6;
  for (int j = 0; j < rounds; ++j) {
    int m = j * 64 + lane;
    float4 p = xwb[m];
    float ab = q.x * p.x + q.y * p.y + q.z * p.z;
    float d2 = fmaxf((qq + p.w) - 2.0f * ab, 0.0f);
    u64 key = ((u64)__float_as_uint(d2) << 32) | (unsigned)m;
    if (key < k15) {
      k15 = key;
      CSWAP(k14, k15); CSWAP(k13, k14); CSWAP(k12, k13); CSWAP(k11, k12);
      CSWAP(k10, k11); CSWAP(k9, k10);  CSWAP(k8, k9);   CSWAP(k7, k8);
      CSWAP(k6, k7);   CSWAP(k5, k6);   CSWAP(k4, k5);   CSWAP(k3, k4);
      CSWAP(k2, k3);   CSWAP(k1, k2);   CSWAP(k0, k1);
    }
  }
  lists[0 * 64 + lane] = k0;   lists[1 * 64 + lane] = k1;
  lists[2 * 64 + lane] = k2;   lists[3 * 64 + lane] = k3;
  lists[4 * 64 + lane] = k4;   lists[5 * 64 + lane] = k5;
  lists[6 * 64 + lane] = k6;   lists[7 * 64 + lane] = k7;
  lists[8 * 64 + lane] = k8;   lists[9 * 64 + lane] = k9;
  lists[10 * 64 + lane] = k10; lists[11 * 64 + lane] = k11;
  lists[12 * 64 + lane] = k12; lists[13 * 64 + lane] = k13;
  lists[14 * 64 + lane] = k14; lists[15 * 64 + lane] = k15;
  __syncthreads();
  int head = 0;
  u64 outk = 0;
  for (int r = 0; r < 16; ++r) {
    u64 h = lists[head * 64 + lane];
    u64 mn = h;
#pragma unroll
    for (int mask = 32; mask; mask >>= 1) {
      u64 o = __shfl_xor(mn, mask);
      if (o < mn) mn = o;
    }
    if (h == mn) head++;
    if (lane == r) outk = mn;
  }
  if (lane < 16) win[lane] = outk;
  __syncthreads();
}

// softmax alphas over 16 neighbor coordinate offsets (all lanes redundant)
__device__ __forceinline__ void lae_alphas(const float4* __restrict__ xwb, int n,
                                           const int* idv, const float* __restrict__ A,
                                           float* al) {
  float ax = A[0], ay = A[1], az = A[2];
  float4 q = xwb[n];
  float mx = -3.0e38f;
#pragma unroll
  for (int k = 0; k < 16; ++k) {
    float4 p = xwb[idv[k]];
    float gx = p.x - q.x, gy = p.y - q.y, gz = p.z - q.z;
    float s = gx * ax + gy * ay + gz * az;
    al[k] = s;
    mx = fmaxf(mx, s);
  }
  float sum = 0.0f;
#pragma unroll
  for (int k = 0; k < 16; ++k) { al[k] = expf(al[k] - mx); sum += al[k]; }
#pragma unroll
  for (int k = 0; k < 16; ++k) al[k] = al[k] / sum;
}

// ---------------------------------------------------------------------------
// FPS body. Contiguous per-thread chunks (pt = tid*PTS+p): lane order == pt
// order, serial '>' keeps lowest pt. u64 key (dist_bits<<32 | ~pt) wave-max
// == (max dist, tie -> lowest pt) == jnp.argmax. Winner lane carries its
// point's COORDS into the cross-wave LDS slot (no sxyz buffer, no dependent
// coord fetch). One barrier per iteration.
// ---------------------------------------------------------------------------
template <int NT, int PTS, int NPT>
__device__ __forceinline__ void fps_body(const float4* __restrict__ xw, int N, int npoint,
                                         int* __restrict__ idx_out,
                                         float4* __restrict__ xw_out, u64* smem, int b,
                                         int tid) {
#pragma clang fp contract(off)
  constexpr int NW = NT / 64;
  constexpr bool FULL = (NT * PTS == NPT);
  u64* sk = smem;                            // [2*NW] keys
  float* scx = (float*)(smem + 2 * NW);      // [2*NW]
  float* scy = scx + 2 * NW;
  float* scz = scy + 2 * NW;
  int* hist = (int*)(scz + 2 * NW);          // [512]
  const float4* xb = xw + (size_t)b * N;
  float px[PTS], py[PTS], pz[PTS], dist[PTS];
#pragma unroll
  for (int p = 0; p < PTS; ++p) {
    int pt = tid * PTS + p;
    if (FULL || pt < N) {
      float4 v = xb[pt];
      px[p] = v.x; py[p] = v.y; pz[p] = v.z;
    } else {
      px[p] = 0.0f; py[p] = 0.0f; pz[p] = 0.0f;
    }
    dist[p] = 1e10f;
  }
  int far = 0;
  float4 c0 = xb[0];
  float cx = c0.x, cy = c0.y, cz = c0.z;
  for (int t = 0; t < npoint; ++t) {
    if (tid == 0) hist[t] = far;
    float bestd = -1.0f;
    int bestp = 0;
    float bx_ = 0.0f, by_ = 0.0f, bz_ = 0.0f;
#pragma unroll
    for (int p = 0; p < PTS; ++p) {
      int pt = tid * PTS + p;
      if (FULL || pt < N) {
        float dx = px[p] - cx, dy = py[p] - cy, dz = pz[p] - cz;
        float d = dx * dx + dy * dy + dz * dz;
        float nd = fminf(dist[p], d);
        dist[p] = nd;
        if (nd > bestd) { bestd = nd; bestp = pt; bx_ = px[p]; by_ = py[p]; bz_ = pz[p]; }
      }
    }
    u64 key = (bestd < 0.0f)
                  ? 0ull
                  : (((u64)__float_as_uint(bestd) << 32) | (unsigned)(~bestp));
    u64 okey = key;
#pragma unroll
    for (int m = 1; m <= 32; m <<= 1) {
      u64 o = __shfl_xor(key, m);
      if (o > key) key = o;
    }
    int par = (t & 1) * NW;
    int wv = tid >> 6;
    if (okey == key) {  // unique winner per wave (keys unique when nonzero)
      sk[par + wv] = key;
      scx[par + wv] = bx_; scy[par + wv] = by_; scz[par + wv] = bz_;
    }
    __syncthreads();
    u64 kk = sk[par + 0];
    float fx = scx[par + 0], fy = scy[par + 0], fz = scz[par + 0];
#pragma unroll
    for (int w = 1; w < NW; ++w) {
      u64 o = sk[par + w];
      float ox = scx[par + w], oy = scy[par + w], oz = scz[par + w];
      if (o > kk) { kk = o; fx = ox; fy = oy; fz = oz; }
    }
    far = (int)(~(unsigned)kk);
    cx = fx; cy = fy; cz = fz;
  }
  __syncthreads();
  for (int s = tid; s < npoint; s += NT) {
    int idp = hist[s];
    idx_out[(size_t)b * npoint + s] = idp;
    xw_out[(size_t)b * npoint + s] = xb[idp];
  }
}

// ---------------------------------------------------------------------------
// knn_gw: kNN + ball filter + softmax-weighted feature sum w/ src indirection
// ---------------------------------------------------------------------------
__device__ __forceinline__ void knn_gw_body(const float4* __restrict__ xw_s, int N, float r2,
                                            int* __restrict__ idxK,
                                            const int* __restrict__ srcmap,
                                            const float* __restrict__ fea_src, int Nsrc,
                                            int Cin, const float* __restrict__ A,
                                            float* __restrict__ wf, int bn, int lane,
                                            u64* lists, u64* win) {
  int b = bn / N, n = bn - b * N;
  const float4* xb = xw_s + (size_t)b * N;
  knn16_search(xb, N, n, lane, lists, win);
  int idv[16];
#pragma unroll
  for (int k = 0; k < 16; ++k) {
    u64 kk = win[k];
    float d2 = __uint_as_float((unsigned)(kk >> 32));
    idv[k] = (d2 <= r2) ? (int)(kk & 0xFFFFFFFFu) : n;
  }
  if (lane < 16) idxK[(size_t)bn * 16 + lane] = idv[lane];
  float al[16];
  lae_alphas(xb, n, idv, A, al);
  int row[16];
  const int* sm = srcmap + (size_t)b * N;
#pragma unroll
  for (int k = 0; k < 16; ++k) row[k] = sm[idv[k]];
  const float* fb = fea_src + (size_t)b * Nsrc * Cin;
  float* wo = wf + (size_t)bn * Cin;
  for (int c = lane; c < Cin; c += 64) {
    float acc = 0.0f;
#pragma unroll
    for (int k = 0; k < 16; ++k) acc += al[k] * fb[(size_t)row[k] * Cin + c];
    wo[c] = acc;
  }
}

// L0 variant: fea == xyz (Cin=3) with fused K=3 mini-GEMM -> fea0 (Cout=64)
__device__ __forceinline__ void knn_gw0_body(const float4* __restrict__ xw, int N, float r2,
                                             int* __restrict__ idxK,
                                             const float* __restrict__ W0,
                                             const float* __restrict__ b0,
                                             const float* __restrict__ A0,
                                             float* __restrict__ fea0, int bn, int lane,
                                             u64* lists, u64* win) {
  int b = bn / N, n = bn - b * N;
  const float4* xb = xw + (size_t)b * N;
  knn16_search(xb, N, n, lane, lists, win);
  int idv[16];
#pragma unroll
  for (int k = 0; k < 16; ++k) {
    u64 kk = win[k];
    float d2 = __uint_as_float((unsigned)(kk >> 32));
    idv[k] = (d2 <= r2) ? (int)(kk & 0xFFFFFFFFu) : n;
  }
  if (lane < 16) idxK[(size_t)bn * 16 + lane] = idv[lane];
  float al[16];
  lae_alphas(xb, n, idv, A0, al);
  float w0 = 0.0f, w1 = 0.0f, w2 = 0.0f;
#pragma unroll
  for (int k = 0; k < 16; ++k) {
    float4 p = xb[idv[k]];
    w0 += al[k] * p.x;
    w1 += al[k] * p.y;
    w2 += al[k] * p.z;
  }
  float v = w0 * W0[0 * 64 + lane] + w1 * W0[1 * 64 + lane] + w2 * W0[2 * 64 + lane] +
            b0[lane];
  fea0[(size_t)bn * 64 + lane] = fmaxf(v, 0.0f);
}

// ---------------------------------------------------------------------------
// 3-NN inverse-distance (pdist2 form, stable top-3)
// ---------------------------------------------------------------------------
__device__ __forceinline__ void interp3_body(const float4* __restrict__ xd,
                                             const float4* __restrict__ xs, int Nd, int Ns,
                                             int* __restrict__ idx3, float* __restrict__ w3,
                                             int gid) {
#pragma clang fp contract(off)
  int b = gid / Nd;
  const float4* xb = xs + (size_t)b * Ns;
  float4 q = xd[gid];
  float qq = q.w;
  float v0 = 3.0e38f, v1 = 3.0e38f, v2 = 3.0e38f;
  int i0 = 0, i1 = 0, i2 = 0;
  for (int m = 0; m < Ns; ++m) {
    float4 p = xb[m];
    float ab = q.x * p.x + q.y * p.y + q.z * p.z;
    float d2 = fmaxf((qq + p.w) - 2.0f * ab, 0.0f);
    if (d2 < v2) {
      if (d2 < v0) { v2 = v1; i2 = i1; v1 = v0; i1 = i0; v0 = d2; i0 = m; }
      else if (d2 < v1) { v2 = v1; i2 = i1; v1 = d2; i1 = m; }
      else { v2 = d2; i2 = m; }
    }
  }
  float w0 = 1.0f / fmaxf(v0, 1e-10f);
  float w1 = 1.0f / fmaxf(v1, 1e-10f);
  float w2 = 1.0f / fmaxf(v2, 1e-10f);
  float s = w0 + w1 + w2;
  idx3[gid * 3 + 0] = i0; idx3[gid * 3 + 1] = i1; idx3[gid * 3 + 2] = i2;
  w3[gid * 3 + 0] = w0 / s; w3[gid * 3 + 1] = w1 / s; w3[gid * 3 + 2] = w2 / s;
}

// ---------------------------------------------------------------------------
// Tiled fp32 GEMM body (explicit tile indices). Block 256 = 64 co x 4 rg.
// ---------------------------------------------------------------------------
__device__ __forceinline__ void gemm_body(int bx, int by, const float* __restrict__ Amat,
                                          const float* __restrict__ W,
                                          const float* __restrict__ bias,
                                          float* __restrict__ out, int K, int Cout, int relu,
                                          float* lds_a) {
  int co = bx * 64 + (threadIdx.x & 63);
  int rg = threadIdx.x >> 6;
  int r0 = by * 32;
  float acc[8];
#pragma unroll
  for (int j = 0; j < 8; ++j) acc[j] = 0.0f;
  for (int k0 = 0; k0 < K; k0 += 32) {
    int row = threadIdx.x >> 3;
    int kq = (threadIdx.x & 7) * 4;
    int gk = k0 + kq;
    const float* ap = Amat + (size_t)(r0 + row) * K + gk;
    float a0 = 0.0f, a1 = 0.0f, a2 = 0.0f, a3 = 0.0f;
    if (gk + 3 < K) {
      float4 tv = *(const float4*)ap;
      a0 = tv.x; a1 = tv.y; a2 = tv.z; a3 = tv.w;
    } else {
      if (gk + 0 < K) a0 = ap[0];
      if (gk + 1 < K) a1 = ap[1];
      if (gk + 2 < K) a2 = ap[2];
    }
    __syncthreads();
    lds_a[(kq + 0) * 36 + row] = a0;
    lds_a[(kq + 1) * 36 + row] = a1;
    lds_a[(kq + 2) * 36 + row] = a2;
    lds_a[(kq + 3) * 36 + row] = a3;
    __syncthreads();
    int kmax = K - k0;
    if (kmax > 32) kmax = 32;
    if (kmax == 32) {
#pragma unroll
      for (int kk = 0; kk < 32; ++kk) {
        float w = W[(size_t)(k0 + kk) * Cout + co];
        const float* ar = &lds_a[kk * 36 + rg * 8];
        float4 x0 = *(const float4*)ar;
        float4 x1 = *(const float4*)(ar + 4);
        acc[0] += x0.x * w; acc[1] += x0.y * w; acc[2] += x0.z * w; acc[3] += x0.w * w;
        acc[4] += x1.x * w; acc[5] += x1.y * w; acc[6] += x1.z * w; acc[7] += x1.w * w;
      }
    } else {
      for (int kk = 0; kk < kmax; ++kk) {
        float w = W[(size_t)(k0 + kk) * Cout + co];
        const float* ar = &lds_a[kk * 36 + rg * 8];
        float4 x0 = *(const float4*)ar;
        float4 x1 = *(const float4*)(ar + 4);
        acc[0] += x0.x * w; acc[1] += x0.y * w; acc[2] += x0.z * w; acc[3] += x0.w * w;
        acc[4] += x1.x * w; acc[5] += x1.y * w; acc[6] += x1.z * w; acc[7] += x1.w * w;
      }
    }
  }
  float bb = bias ? bias[co] : 0.0f;
#pragma unroll
  for (int j = 0; j < 8; ++j) {
    int r = r0 + rg * 8 + j;
    float vv = acc[j] + bb;
    if (relu) vv = fmaxf(vv, 0.0f);
    out[(size_t)r * Cout + co] = vv;
  }
}

// interp-add: Y[r][c] += sum_j w3[r][j] * Zb[i3[r][j]][c]
__device__ __forceinline__ void interp_add_body(float* __restrict__ Y,
                                                const int* __restrict__ i3,
                                                const float* __restrict__ w3,
                                                const float* __restrict__ Zb, int Nd, int Ns,
                                                int C, int gid) {
  int c = gid % C;
  int r = gid / C;
  int b = r / Nd;
  const int* ii = i3 + (size_t)r * 3;
  const float* ww = w3 + (size_t)r * 3;
  const float* zb = Zb + (size_t)b * Ns * C;
  Y[gid] += ww[0] * zb[(size_t)ii[0] * C + c] + ww[1] * zb[(size_t)ii[1] * C + c] +
            ww[2] * zb[(size_t)ii[2] * C + c];
}

// gwpost: out = relu(sum_k al_k Y[idx_k][c] + b[c]) ; one wave per point
__device__ __forceinline__ void gwpost_body(const float4* __restrict__ xw,
                                            const float* __restrict__ Y,
                                            const int* __restrict__ knn,
                                            const float* __restrict__ A,
                                            const float* __restrict__ bias,
                                            float* __restrict__ out, int N, int C, int bn,
                                            int lane) {
  int b = bn / N, n = bn - b * N;
  const float4* xb = xw + (size_t)b * N;
  const int* kn = knn + (size_t)bn * 16;
  int idv[16];
#pragma unroll
  for (int k = 0; k < 16; ++k) idv[k] = kn[k];
  float al[16];
  lae_alphas(xb, n, idv, A, al);
  const float* Yb = Y + (size_t)b * N * C;
  float* wo = out + (size_t)bn * C;
  for (int c = lane; c < C; c += 64) {
    float acc = 0.0f;
#pragma unroll
    for (int k = 0; k < 16; ++k) acc += al[k] * Yb[(size_t)idv[k] * C + c];
    wo[c] = fmaxf(acc + bias[c], 0.0f);
  }
}

// L6 gwpost + final classifier (C=128), out (B,13,N)
__device__ __forceinline__ void gwfinal_body(const float4* __restrict__ xw,
                                             const float* __restrict__ Y,
                                             const int* __restrict__ knn,
                                             const float* __restrict__ A,
                                             const float* __restrict__ bias,
                                             const float* __restrict__ Wf,
                                             const float* __restrict__ bfv,
                                             float* __restrict__ out, int N, int bn,
                                             int lane) {
  int b = bn / N, n = bn - b * N;
  const float4* xb = xw + (size_t)b * N;
  const int* kn = knn + (size_t)bn * 16;
  int idv[16];
#pragma unroll
  for (int k = 0; k < 16; ++k) idv[k] = kn[k];
  float al[16];
  lae_alphas(xb, n, idv, A, al);
  const float* Yb = Y + (size_t)b * N * 128;
  float a0 = 0.0f, a1 = 0.0f;
#pragma unroll
  for (int k = 0; k < 16; ++k) {
    const float* yr = Yb + (size_t)idv[k] * 128;
    a0 += al[k] * yr[lane];
    a1 += al[k] * yr[lane + 64];
  }
  float v0 = fmaxf(a0 + bias[lane], 0.0f);
  float v1 = fmaxf(a1 + bias[lane + 64], 0.0f);
  float* ob = out + ((size_t)b * 13) * N + n;
#pragma unroll
  for (int cls = 0; cls < 13; ++cls) {
    float p = v0 * Wf[lane * 13 + cls] + v1 * Wf[(lane + 64) * 13 + cls];
#pragma unroll
    for (int m = 32; m; m >>= 1) p += __shfl_xor(p, m);
    if (lane == 0) ob[(size_t)cls * N] = p + bfv[cls];
  }
}

// attn: out[n] = softmax(q[n].k^T) @ v + fea[n] ; 128 threads per (b,n) pair
__device__ __forceinline__ void attn_body(const float* __restrict__ q,
                                          const float* __restrict__ k,
                                          const float* __restrict__ v,
                                          const float* __restrict__ fea,
                                          float* __restrict__ out, int N, int C, int b,
                                          int n, int t, float* sa, float* sb) {
  const float* qn = q + ((size_t)b * N + n) * C;
  if (t < N) {
    const float4* km = (const float4*)(k + ((size_t)b * N + t) * C);
    const float4* q4 = (const float4*)qn;
    float acc = 0.0f;
    int C4 = C >> 2;
    for (int c = 0; c < C4; ++c) {
      float4 kv = km[c];
      float4 qv = q4[c];
      acc += qv.x * kv.x + qv.y * kv.y + qv.z * kv.z + qv.w * kv.w;
    }
    sa[t] = acc;
  }
  __syncthreads();
  float mx = -3.0e38f;
  for (int i = 0; i < N; ++i) mx = fmaxf(mx, sa[i]);
  if (t < N) sb[t] = expf(sa[t] - mx);
  __syncthreads();
  float sum = 0.0f;
  for (int i = 0; i < N; ++i) sum += sb[i];
  size_t rowo = ((size_t)b * N + n) * C;
  for (int c = t; c < C; c += 128) {
    float acc = 0.0f;
    for (int m = 0; m < N; ++m) acc += sb[m] * v[((size_t)b * N + m) * C + c];
    out[rowo + c] = acc / sum + fea[rowo + c];
  }
}

// ---------------------------------------------------------------------------
// Mega kernel: 23 stages separated by grid barriers. LDS = 33280B union.
// ---------------------------------------------------------------------------
__global__ __launch_bounds__(256) void pan_mega(PanP p) {
  __shared__ u64 smem[4160];
  const int bid = blockIdx.x, tid = threadIdx.x;
  const int wave = tid >> 6, lane = tid & 63;
  u64* lists = smem + (size_t)wave * 1024;
  u64* win = smem + 4096 + wave * 16;
  float* ldsf = (float*)smem;

  // S0: pack coords + norms
  for (int i = bid * 256 + tid; i < NBATCH * 4096; i += NBLK * 256) {
#pragma clang fp contract(off)
    float x = p.xyz[3 * i + 0], y = p.xyz[3 * i + 1], z = p.xyz[3 * i + 2];
    p.xw0[i] = make_float4(x, y, z, x * x + y * y + z * z);
  }
  gsync(p.bar);

  // S1: fps 4096->512 (blocks 0..3) || knn_gw0 (4096 units x 4 queries)
  if (bid < NBATCH) {
    fps_body<256, 16, 4096>(p.xw0, 4096, 512, p.idx1, p.xw1, smem, bid, tid);
  } else {
    for (int u = bid - NBATCH; u < 4096; u += NBLK - NBATCH) {
      knn_gw0_body(p.xw0, 4096, p.r2_0, p.idxK0, p.W0, p.b0, p.A0, p.fea0, u * 4 + wave,
                   lane, lists, win);
    }
  }
  gsync(p.bar);

  // S2: fps 512->128 || knn L1 (512u) || interp0 (64u) || Y6a gemm (1024u)
  if (bid < NBATCH) {
    fps_body<256, 2, 512>(p.xw1, 512, 128, p.idx2, p.xw2, smem, bid, tid);
  } else {
    for (int u = bid - NBATCH; u < 1600; u += NBLK - NBATCH) {
      if (u < 512) {
        knn_gw_body(p.xw1, 512, p.r2_1, p.idxK1, p.idx1, p.fea0, 4096, 64, p.A1, p.wfb,
                    u * 4 + wave, lane, lists, win);
      } else if (u < 576) {
        interp3_body(p.xw0, p.xw1, 4096, 512, p.idxI0, p.wI0, (u - 512) * 256 + tid);
      } else {
        int gb = u - 576;
        gemm_body(gb & 1, gb >> 1, p.fea0, p.W6, nullptr, p.Y6, 64, 128, 0, ldsf);
      }
    }
  }
  gsync(p.bar);

  // S3: gemm L1 -> fea1 (2 x 64 tiles)
  for (int u = bid; u < 128; u += NBLK)
    gemm_body(u & 1, u >> 1, p.wfb, p.W1, p.b1, p.fea1, 64, 128, 1, ldsf);
  gsync(p.bar);

  // S4: fps 128->64 || knn L2 (128u) || interp1 (8u) || Y5a gemm (256u)
  if (bid < NBATCH) {
    fps_body<256, 1, 128>(p.xw2, 128, 64, p.idx3, p.xw3, smem, bid, tid);
  } else {
    for (int u = bid - NBATCH; u < 392; u += NBLK - NBATCH) {
      if (u < 128) {
        knn_gw_body(p.xw2, 128, p.r2_2, p.idxK2, p.idx2, p.fea1, 512, 128, p.A2, p.wfb,
                    u * 4 + wave, lane, lists, win);
      } else if (u < 136) {
        interp3_body(p.xw1, p.xw2, 512, 128, p.idxI1, p.wI1, (u - 128) * 256 + tid);
      } else {
        int gb = u - 136;
        gemm_body(gb & 3, gb >> 2, p.fea1, p.W5, nullptr, p.Y5, 128, 256, 0, ldsf);
      }
    }
  }
  gsync(p.bar);

  // S5: gemm L2 -> fea2a (4 x 16)
  for (int u = bid; u < 64; u += NBLK)
    gemm_body(u & 3, u >> 2, p.wfb, p.W2, p.b2, p.fea2a, 128, 256, 1, ldsf);
  gsync(p.bar);

  // S6: qkv1 (3 x 64)
  for (int u = bid; u < 192; u += NBLK) {
    int z = u / 64, r = u % 64;
    const float* W = z == 0 ? p.Wq1 : (z == 1 ? p.Wk1 : p.Wv1);
    float* o = z == 0 ? p.qb : (z == 1 ? p.kb : p.vb);
    gemm_body(r & 3, r >> 2, p.fea2a, W, nullptr, o, 256, 256, 0, ldsf);
  }
  gsync(p.bar);

  // S7: attn1 -> fea2b (512 pairs, 2 per block)
  {
    int half = tid >> 7, t = tid & 127;
    for (int u = bid; u < 256; u += NBLK) {
      int pair = u * 2 + half;
      attn_body(p.qb, p.kb, p.vb, p.fea2a, p.fea2b, 128, 256, pair / 128, pair % 128, t,
                ldsf + half * 128, ldsf + 256 + half * 128);
    }
  }
  gsync(p.bar);

  // S8: knn L3 (64u) || interp2 (2u) || Y4a gemm (64u)
  for (int u = bid; u < 130; u += NBLK) {
    if (u < 64) {
      knn_gw_body(p.xw3, 64, p.r2_3, p.idxK3, p.idx3, p.fea2b, 128, 256, p.A3, p.wfb,
                  u * 4 + wave, lane, lists, win);
    } else if (u < 66) {
      interp3_body(p.xw2, p.xw3, 128, 64, p.idxI2, p.wI2, (u - 64) * 256 + tid);
    } else {
      int gb = u - 66;
      gemm_body(gb & 3, gb >> 2, p.fea2b, p.W4, nullptr, p.Y4, 256, 256, 0, ldsf);
    }
  }
  gsync(p.bar);

  // S9: gemm L3 -> fea3a (8 x 8)
  for (int u = bid; u < 64; u += NBLK)
    gemm_body(u & 7, u >> 3, p.wfb, p.W3, p.b3, p.fea3a, 256, 512, 1, ldsf);
  gsync(p.bar);

  // S10: qkv2 (3 x 64)
  for (int u = bid; u < 192; u += NBLK) {
    int z = u / 64, r = u % 64;
    const float* W = z == 0 ? p.Wq2 : (z == 1 ? p.Wk2 : p.Wv2);
    float* o = z == 0 ? p.qb : (z == 1 ? p.kb : p.vb);
    gemm_body(r & 7, r >> 3, p.fea3a, W, nullptr, o, 512, 512, 0, ldsf);
  }
  gsync(p.bar);

  // S11: attn2 -> fea3b (256 pairs)
  {
    int half = tid >> 7, t = tid & 127;
    for (int u = bid; u < 128; u += NBLK) {
      int pair = u * 2 + half;
      attn_body(p.qb, p.kb, p.vb, p.fea3a, p.fea3b, 64, 512, pair / 64, pair % 64, t,
                ldsf + half * 128, ldsf + 256 + half * 128);
    }
  }
  gsync(p.bar);

  // S12: Zb4 = fea3b @ W4b (4 x 8)
  for (int u = bid; u < 32; u += NBLK)
    gemm_body(u & 3, u >> 2, p.fea3b, p.W4 + 256 * 256, nullptr, p.Zb4, 512, 256, 0, ldsf);
  gsync(p.bar);

  // S13: Y4 += interp(Zb4)  (512 units x 256)
  for (int u = bid; u < 512; u += NBLK)
    interp_add_body(p.Y4, p.idxI2, p.wI2, p.Zb4, 128, 64, 256, u * 256 + tid);
  gsync(p.bar);

  // S14: gwpost -> fea2c (128 units x 4 waves)
  for (int u = bid; u < 128; u += NBLK)
    gwpost_body(p.xw2, p.Y4, p.idxK2, p.A4, p.b4, p.fea2c, 128, 256, u * 4 + wave, lane);
  gsync(p.bar);

  // S15: qkv3 (3 x 64)
  for (int u = bid; u < 192; u += NBLK) {
    int z = u / 64, r = u % 64;
    const float* W = z == 0 ? p.Wq3 : (z == 1 ? p.Wk3 : p.Wv3);
    float* o = z == 0 ? p.qb : (z == 1 ? p.kb : p.vb);
    gemm_body(r & 3, r >> 2, p.fea2c, W, nullptr, o, 256, 256, 0, ldsf);
  }
  gsync(p.bar);

  // S16: attn3 -> fea2d (512 pairs)
  {
    int half = tid >> 7, t = tid & 127;
    for (int u = bid; u < 256; u += NBLK) {
      int pair = u * 2 + half;
      attn_body(p.qb, p.kb, p.vb, p.fea2c, p.fea2d, 128, 256, pair / 128, pair % 128, t,
                ldsf + half * 128, ldsf + 256 + half * 128);
    }
  }
  gsync(p.bar);

  // S17: Zb5 = fea2d @ W5b (4 x 16)
  for (int u = bid; u < 64; u += NBLK)
    gemm_body(u & 3, u >> 2, p.fea2d, p.W5 + 128 * 256, nullptr, p.Zb5, 256, 256, 0, ldsf);
  gsync(p.bar);

  // S18: Y5 += interp(Zb5)  (2048 units)
  for (int u = bid; u < 2048; u += NBLK)
    interp_add_body(p.Y5, p.idxI1, p.wI1, p.Zb5, 512, 128, 256, u * 256 + tid);
  gsync(p.bar);

  // S19: gwpost -> fea1b (512 units)
  for (int u = bid; u < 512; u += NBLK)
    gwpost_body(p.xw1, p.Y5, p.idxK1, p.A5, p.b5, p.fea1b, 512, 256, u * 4 + wave, lane);
  gsync(p.bar);

  // S20: Zb6 = fea1b @ W6b (2 x 64)
  for (int u = bid; u < 128; u += NBLK)
    gemm_body(u & 1, u >> 1, p.fea1b, p.W6 + 64 * 128, nullptr, p.Zb6, 256, 128, 0, ldsf);
  gsync(p.bar);

  // S21: Y6 += interp(Zb6)  (8192 units)
  for (int u = bid; u < 8192; u += NBLK)
    interp_add_body(p.Y6, p.idxI0, p.wI0, p.Zb6, 4096, 512, 128, u * 256 + tid);
  gsync(p.bar);

  // S22: gwpost + final -> out (4096 units x 4 waves)
  for (int u = bid; u < 4096; u += NBLK)
    gwfinal_body(p.xw0, p.Y6, p.idxK0, p.A6, p.b6, p.Wf, p.bf, p.out, 4096, u * 4 + wave,
                 lane);
}

// ---------------------------------------------------------------------------
extern "C" void kernel_launch(void* const* d_in, const int* in_sizes, int n_in,
                              void* d_out, int out_size, void* d_ws, size_t ws_size,
                              hipStream_t stream) {
  (void)in_sizes; (void)n_in; (void)out_size; (void)ws_size;
  const int B = NBATCH, N0 = 4096, N1 = 512, N2 = 128, N3 = 64;
  char* base = (char*)d_ws;
  size_t off = 256;  // first 256B reserved for the grid barrier (zeroed below)
  auto alloc = [&](size_t bytes) -> void* {
    void* pp = base + off;
    off += (bytes + 255) & ~(size_t)255;
    return pp;
  };

  PanP p;
  p.bar = (unsigned*)d_ws;
  p.xyz = (const float*)d_in[0];
  const float** Wp[7] = {&p.W0, &p.W1, &p.W2, &p.W3, &p.W4, &p.W5, &p.W6};
  const float** bp[7] = {&p.b0, &p.b1, &p.b2, &p.b3, &p.b4, &p.b5, &p.b6};
  const float** Ap[7] = {&p.A0, &p.A1, &p.A2, &p.A3, &p.A4, &p.A5, &p.A6};
  for (int i = 0; i < 7; ++i) {
    *Wp[i] = (const float*)d_in[1 + 3 * i];
    *bp[i] = (const float*)d_in[2 + 3 * i];
    *Ap[i] = (const float*)d_in[3 + 3 * i];
  }
  p.Wq1 = (const float*)d_in[22]; p.Wk1 = (const float*)d_in[23];
  p.Wv1 = (const float*)d_in[24]; p.Wq2 = (const float*)d_in[25];
  p.Wk2 = (const float*)d_in[26]; p.Wv2 = (const float*)d_in[27];
  p.Wq3 = (const float*)d_in[28]; p.Wk3 = (const float*)d_in[29];
  p.Wv3 = (const float*)d_in[30]; p.Wf = (const float*)d_in[31];
  p.bf = (const float*)d_in[32];
  p.out = (float*)d_out;

  p.xw0 = (float4*)alloc((size_t)B * N0 * 16);
  p.xw1 = (float4*)alloc((size_t)B * N1 * 16);
  p.xw2 = (float4*)alloc((size_t)B * N2 * 16);
  p.xw3 = (float4*)alloc((size_t)B * N3 * 16);
  p.idxK0 = (int*)alloc((size_t)B * N0 * 16 * 4);
  p.idxK1 = (int*)alloc((size_t)B * N1 * 16 * 4);
  p.idxK2 = (int*)alloc((size_t)B * N2 * 16 * 4);
  p.idxK3 = (int*)alloc((size_t)B * N3 * 16 * 4);
  p.idx1 = (int*)alloc((size_t)B * N1 * 4);
  p.idx2 = (int*)alloc((size_t)B * N2 * 4);
  p.idx3 = (int*)alloc((size_t)B * N3 * 4);
  p.fea0 = (float*)alloc((size_t)B * N0 * 64 * 4);
  p.fea1 = (float*)alloc((size_t)B * N1 * 128 * 4);
  p.fea1b = (float*)alloc((size_t)B * N1 * 256 * 4);
  p.fea2a = (float*)alloc((size_t)B * N2 * 256 * 4);
  p.fea2b = (float*)alloc((size_t)B * N2 * 256 * 4);
  p.fea2c = (float*)alloc((size_t)B * N2 * 256 * 4);
  p.fea2d = (float*)alloc((size_t)B * N2 * 256 * 4);
  p.fea3a = (float*)alloc((size_t)B * N3 * 512 * 4);
  p.fea3b = (float*)alloc((size_t)B * N3 * 512 * 4);
  p.qb = (float*)alloc((size_t)B * 32768 * 4);
  p.kb = (float*)alloc((size_t)B * 32768 * 4);
  p.vb = (float*)alloc((size_t)B * 32768 * 4);
  p.idxI2 = (int*)alloc((size_t)B * N2 * 3 * 4);
  p.wI2 = (float*)alloc((size_t)B * N2 * 3 * 4);
  p.idxI1 = (int*)alloc((size_t)B * N1 * 3 * 4);
  p.wI1 = (float*)alloc((size_t)B * N1 * 3 * 4);
  p.idxI0 = (int*)alloc((size_t)B * N0 * 3 * 4);
  p.wI0 = (float*)alloc((size_t)B * N0 * 3 * 4);
  p.Zb4 = (float*)alloc((size_t)B * N3 * 256 * 4);
  p.Zb5 = (float*)alloc((size_t)B * N2 * 256 * 4);
  p.Zb6 = (float*)alloc((size_t)B * N1 * 128 * 4);
  p.Y4 = (float*)alloc((size_t)B * N2 * 256 * 4);
  p.Y5 = (float*)alloc((size_t)B * N1 * 256 * 4);
  p.Y6 = (float*)alloc((size_t)B * N0 * 128 * 4);
  p.wfb = (float*)alloc((size_t)B * N0 * 320 * 4);

  p.r2_0 = (float)(0.06 * 0.06);
  p.r2_1 = (float)(0.12 * 0.12);
  p.r2_2 = (float)(0.3 * 0.3);
  p.r2_3 = (float)(0.5 * 0.5);

  // zero the grid barrier (captured into the graph -> re-zeroed every replay)
  hipMemsetAsync(d_ws, 0, 8, stream);
  pan_mega<<<NBLK, 256, 0, stream>>>(p);
}

// Round 11
// 1025.718 us; speedup vs baseline: 3.8784x; 3.8784x over previous
//
#include <hip/hip_runtime.h>
#include <math.h>

#define NB 4  // batch

typedef unsigned long long u64;

// branchless ascending compare-swap on u64 keys
#define CSWAP(a, b)                                          \
  {                                                          \
    u64 _mn = (b < a) ? b : a;                               \
    u64 _mx = (b < a) ? a : b;                               \
    a = _mn;                                                 \
    b = _mx;                                                 \
  }

// ---------------------------------------------------------------------------
// Pack xyz (stride 3) -> xyzw float4 with norm (left-assoc, contract off:
// bit-identical to reference pdist2 norms).
// ---------------------------------------------------------------------------
__global__ __launch_bounds__(256) void norms_kernel(const float* __restrict__ xyz,
                                                    float4* __restrict__ xw, int total) {
#pragma clang fp contract(off)
  int i = blockIdx.x * 256 + threadIdx.x;
  if (i >= total) return;
  float x = xyz[3 * i + 0], y = xyz[3 * i + 1], z = xyz[3 * i + 2];
  xw[i] = make_float4(x, y, z, x * x + y * y + z * z);
}

// ---------------------------------------------------------------------------
// kNN-16 top-16 search (per-wave) on packed float4 coords. Key =
// (d2_bits<<32)|idx == exact (d2, idx) lexicographic order == stable top_k.
// ---------------------------------------------------------------------------
__device__ __forceinline__ void knn16_search(const float4* __restrict__ xwb, int N, int n,
                                             int lane, u64* lists, u64* win) {
#pragma clang fp contract(off)
  float4 q = xwb[n];
  float qq = q.w;
  const u64 SENT = ((u64)0x7F800000u << 32) | (unsigned)lane;
  u64 k0 = SENT, k1 = SENT, k2 = SENT, k3 = SENT, k4 = SENT, k5 = SENT, k6 = SENT,
      k7 = SENT, k8 = SENT, k9 = SENT, k10 = SENT, k11 = SENT, k12 = SENT, k13 = SENT,
      k14 = SENT, k15 = SENT;
  int rounds = N >> 6;
  for (int j = 0; j < rounds; ++j) {
    int m = j * 64 + lane;
    float4 p = xwb[m];
    float ab = q.x * p.x + q.y * p.y + q.z * p.z;
    float d2 = fmaxf((qq + p.w) - 2.0f * ab, 0.0f);
    u64 key = ((u64)__float_as_uint(d2) << 32) | (unsigned)m;
    if (key < k15) {
      k15 = key;
      CSWAP(k14, k15); CSWAP(k13, k14); CSWAP(k12, k13); CSWAP(k11, k12);
      CSWAP(k10, k11); CSWAP(k9, k10);  CSWAP(k8, k9);   CSWAP(k7, k8);
      CSWAP(k6, k7);   CSWAP(k5, k6);   CSWAP(k4, k5);   CSWAP(k3, k4);
      CSWAP(k2, k3);   CSWAP(k1, k2);   CSWAP(k0, k1);
    }
  }
  lists[0 * 64 + lane] = k0;   lists[1 * 64 + lane] = k1;
  lists[2 * 64 + lane] = k2;   lists[3 * 64 + lane] = k3;
  lists[4 * 64 + lane] = k4;   lists[5 * 64 + lane] = k5;
  lists[6 * 64 + lane] = k6;   lists[7 * 64 + lane] = k7;
  lists[8 * 64 + lane] = k8;   lists[9 * 64 + lane] = k9;
  lists[10 * 64 + lane] = k10; lists[11 * 64 + lane] = k11;
  lists[12 * 64 + lane] = k12; lists[13 * 64 + lane] = k13;
  lists[14 * 64 + lane] = k14; lists[15 * 64 + lane] = k15;
  __syncthreads();
  int head = 0;
  u64 outk = 0;
  for (int r = 0; r < 16; ++r) {
    u64 h = lists[head * 64 + lane];
    u64 mn = h;
#pragma unroll
    for (int mask = 32; mask; mask >>= 1) {
      u64 o = __shfl_xor(mn, mask);
      if (o < mn) mn = o;
    }
    if (h == mn) head++;
    if (lane == r) outk = mn;
  }
  if (lane < 16) win[lane] = outk;
  __syncthreads();
}

// softmax alphas over 16 neighbor coordinate offsets (all lanes redundant)
__device__ __forceinline__ void lae_alphas(const float4* __restrict__ xwb, int n,
                                           const int* idv, const float* __restrict__ A,
                                           float* al) {
  float ax = A[0], ay = A[1], az = A[2];
  float4 q = xwb[n];
  float mx = -3.0e38f;
#pragma unroll
  for (int k = 0; k < 16; ++k) {
    float4 p = xwb[idv[k]];
    float gx = p.x - q.x, gy = p.y - q.y, gz = p.z - q.z;
    float s = gx * ax + gy * ay + gz * az;
    al[k] = s;
    mx = fmaxf(mx, s);
  }
  float sum = 0.0f;
#pragma unroll
  for (int k = 0; k < 16; ++k) { al[k] = expf(al[k] - mx); sum += al[k]; }
#pragma unroll
  for (int k = 0; k < 16; ++k) al[k] = al[k] / sum;
}

// ---------------------------------------------------------------------------
// FPS body (validated in R9 run). Contiguous per-thread chunks (pt=tid*PTS+p):
// lane order == pt order, serial '>' keeps lowest pt. u64 key
// (dist_bits<<32 | ~pt) wave-max == (max dist, tie -> lowest pt) ==
// jnp.argmax. Winner lane carries its point's COORDS into the cross-wave LDS
// slot (no sxyz buffer, no dependent coord fetch). One barrier per iter.
// ---------------------------------------------------------------------------
template <int NT, int PTS, int NPT>
__device__ __forceinline__ void fps_body(const float4* __restrict__ xw, int N, int npoint,
                                         int* __restrict__ idx_out,
                                         float4* __restrict__ xw_out, u64* smem, int b,
                                         int tid) {
#pragma clang fp contract(off)
  constexpr int NW = NT / 64;
  constexpr bool FULL = (NT * PTS == NPT);
  u64* sk = smem;                            // [2*NW] keys
  float* scx = (float*)(smem + 2 * NW);      // [2*NW]
  float* scy = scx + 2 * NW;
  float* scz = scy + 2 * NW;
  int* hist = (int*)(scz + 2 * NW);          // [512]
  const float4* xb = xw + (size_t)b * N;
  float px[PTS], py[PTS], pz[PTS], dist[PTS];
#pragma unroll
  for (int p = 0; p < PTS; ++p) {
    int pt = tid * PTS + p;
    if (FULL || pt < N) {
      float4 v = xb[pt];
      px[p] = v.x; py[p] = v.y; pz[p] = v.z;
    } else {
      px[p] = 0.0f; py[p] = 0.0f; pz[p] = 0.0f;
    }
    dist[p] = 1e10f;
  }
  int far = 0;
  float4 c0 = xb[0];
  float cx = c0.x, cy = c0.y, cz = c0.z;
  for (int t = 0; t < npoint; ++t) {
    if (tid == 0) hist[t] = far;
    float bestd = -1.0f;
    int bestp = 0;
    float bx_ = 0.0f, by_ = 0.0f, bz_ = 0.0f;
#pragma unroll
    for (int p = 0; p < PTS; ++p) {
      int pt = tid * PTS + p;
      if (FULL || pt < N) {
        float dx = px[p] - cx, dy = py[p] - cy, dz = pz[p] - cz;
        float d = dx * dx + dy * dy + dz * dz;
        float nd = fminf(dist[p], d);
        dist[p] = nd;
        if (nd > bestd) { bestd = nd; bestp = pt; bx_ = px[p]; by_ = py[p]; bz_ = pz[p]; }
      }
    }
    u64 key = (bestd < 0.0f)
                  ? 0ull
                  : (((u64)__float_as_uint(bestd) << 32) | (unsigned)(~bestp));
    u64 okey = key;
#pragma unroll
    for (int m = 1; m <= 32; m <<= 1) {
      u64 o = __shfl_xor(key, m);
      if (o > key) key = o;
    }
    int par = (t & 1) * NW;
    int wv = tid >> 6;
    if (okey == key && bestd >= 0.0f) {  // unique winner per wave
      sk[par + wv] = key;
      scx[par + wv] = bx_; scy[par + wv] = by_; scz[par + wv] = bz_;
    }
    __syncthreads();
    u64 kk = sk[par + 0];
    float fx = scx[par + 0], fy = scy[par + 0], fz = scz[par + 0];
#pragma unroll
    for (int w = 1; w < NW; ++w) {
      u64 o = sk[par + w];
      float ox = scx[par + w], oy = scy[par + w], oz = scz[par + w];
      if (o > kk) { kk = o; fx = ox; fy = oy; fz = oz; }
    }
    far = (int)(~(unsigned)kk);
    cx = fx; cy = fy; cz = fz;
  }
  __syncthreads();
  for (int s = tid; s < npoint; s += NT) {
    int idp = hist[s];
    idx_out[(size_t)b * npoint + s] = idp;
    xw_out[(size_t)b * npoint + s] = xb[idp];
  }
}

// ---------------------------------------------------------------------------
// knn_gw body: kNN + ball filter + softmax-weighted feature sum with source
// row indirection. One wave per query.
// ---------------------------------------------------------------------------
__device__ __forceinline__ void knn_gw_body(const float4* __restrict__ xw_s, int N, float r2,
                                            int* __restrict__ idxK,
                                            const int* __restrict__ srcmap,
                                            const float* __restrict__ fea_src, int Nsrc,
                                            int Cin, const float* __restrict__ A,
                                            float* __restrict__ wf, int bn, int lane,
                                            u64* lists, u64* win) {
  int b = bn / N, n = bn - b * N;
  const float4* xb = xw_s + (size_t)b * N;
  knn16_search(xb, N, n, lane, lists, win);
  int idv[16];
#pragma unroll
  for (int k = 0; k < 16; ++k) {
    u64 kk = win[k];
    float d2 = __uint_as_float((unsigned)(kk >> 32));
    idv[k] = (d2 <= r2) ? (int)(kk & 0xFFFFFFFFu) : n;
  }
  if (lane < 16) idxK[(size_t)bn * 16 + lane] = idv[lane];
  float al[16];
  lae_alphas(xb, n, idv, A, al);
  int row[16];
  const int* sm = srcmap + (size_t)b * N;
#pragma unroll
  for (int k = 0; k < 16; ++k) row[k] = sm[idv[k]];
  const float* fb = fea_src + (size_t)b * Nsrc * Cin;
  float* wo = wf + (size_t)bn * Cin;
  for (int c = lane; c < Cin; c += 64) {
    float acc = 0.0f;
#pragma unroll
    for (int k = 0; k < 16; ++k) acc += al[k] * fb[(size_t)row[k] * Cin + c];
    wo[c] = acc;
  }
}

// L0 variant: fea == xyz (Cin=3) with fused K=3 mini-GEMM -> fea0 (Cout=64)
__device__ __forceinline__ void knn_gw0_body(const float4* __restrict__ xw, int N, float r2,
                                             int* __restrict__ idxK,
                                             const float* __restrict__ W0,
                                             const float* __restrict__ b0,
                                             const float* __restrict__ A0,
                                             float* __restrict__ fea0, int bn, int lane,
                                             u64* lists, u64* win) {
  int b = bn / N, n = bn - b * N;
  const float4* xb = xw + (size_t)b * N;
  knn16_search(xb, N, n, lane, lists, win);
  int idv[16];
#pragma unroll
  for (int k = 0; k < 16; ++k) {
    u64 kk = win[k];
    float d2 = __uint_as_float((unsigned)(kk >> 32));
    idv[k] = (d2 <= r2) ? (int)(kk & 0xFFFFFFFFu) : n;
  }
  if (lane < 16) idxK[(size_t)bn * 16 + lane] = idv[lane];
  float al[16];
  lae_alphas(xb, n, idv, A0, al);
  float w0 = 0.0f, w1 = 0.0f, w2 = 0.0f;
#pragma unroll
  for (int k = 0; k < 16; ++k) {
    float4 p = xb[idv[k]];
    w0 += al[k] * p.x;
    w1 += al[k] * p.y;
    w2 += al[k] * p.z;
  }
  float v = w0 * W0[0 * 64 + lane] + w1 * W0[1 * 64 + lane] + w2 * W0[2 * 64 + lane] +
            b0[lane];
  fea0[(size_t)bn * 64 + lane] = fmaxf(v, 0.0f);
}

// ---------------------------------------------------------------------------
// 3-NN inverse-distance body (pdist2 form, stable top-3), packed coords.
// ---------------------------------------------------------------------------
__device__ __forceinline__ void interp3_body(const float4* __restrict__ xd,
                                             const float4* __restrict__ xs, int Nd, int Ns,
                                             int* __restrict__ idx3, float* __restrict__ w3,
                                             int gid) {
#pragma clang fp contract(off)
  int b = gid / Nd;
  const float4* xb = xs + (size_t)b * Ns;
  float4 q = xd[gid];
  float qq = q.w;
  float v0 = 3.0e38f, v1 = 3.0e38f, v2 = 3.0e38f;
  int i0 = 0, i1 = 0, i2 = 0;
  for (int m = 0; m < Ns; ++m) {
    float4 p = xb[m];
    float ab = q.x * p.x + q.y * p.y + q.z * p.z;
    float d2 = fmaxf((qq + p.w) - 2.0f * ab, 0.0f);
    if (d2 < v2) {
      if (d2 < v0) { v2 = v1; i2 = i1; v1 = v0; i1 = i0; v0 = d2; i0 = m; }
      else if (d2 < v1) { v2 = v1; i2 = i1; v1 = d2; i1 = m; }
      else { v2 = d2; i2 = m; }
    }
  }
  float w0 = 1.0f / fmaxf(v0, 1e-10f);
  float w1 = 1.0f / fmaxf(v1, 1e-10f);
  float w2 = 1.0f / fmaxf(v2, 1e-10f);
  float s = w0 + w1 + w2;
  idx3[gid * 3 + 0] = i0; idx3[gid * 3 + 1] = i1; idx3[gid * 3 + 2] = i2;
  w3[gid * 3 + 0] = w0 / s; w3[gid * 3 + 1] = w1 / s; w3[gid * 3 + 2] = w2 / s;
}

// ---------------------------------------------------------------------------
// Tiled fp32 GEMM body (tile bx, by given explicitly so combos can pack it).
// Block 256 = 64 couts x 4 row-groups; tile 32 rows x 64 couts.
// ---------------------------------------------------------------------------
__device__ __forceinline__ void gemm_body(int bx, int by, const float* __restrict__ Amat,
                                          const float* __restrict__ W,
                                          const float* __restrict__ bias,
                                          float* __restrict__ out, int K, int Cout, int relu,
                                          float* lds_a) {
  int co = bx * 64 + (threadIdx.x & 63);
  int rg = threadIdx.x >> 6;
  int r0 = by * 32;
  float acc[8];
#pragma unroll
  for (int j = 0; j < 8; ++j) acc[j] = 0.0f;
  for (int k0 = 0; k0 < K; k0 += 32) {
    int row = threadIdx.x >> 3;
    int kq = (threadIdx.x & 7) * 4;
    int gk = k0 + kq;
    const float* ap = Amat + (size_t)(r0 + row) * K + gk;
    float a0 = 0.0f, a1 = 0.0f, a2 = 0.0f, a3 = 0.0f;
    if (gk + 3 < K) {
      float4 tv = *(const float4*)ap;
      a0 = tv.x; a1 = tv.y; a2 = tv.z; a3 = tv.w;
    } else {
      if (gk + 0 < K) a0 = ap[0];
      if (gk + 1 < K) a1 = ap[1];
      if (gk + 2 < K) a2 = ap[2];
    }
    __syncthreads();
    lds_a[(kq + 0) * 36 + row] = a0;
    lds_a[(kq + 1) * 36 + row] = a1;
    lds_a[(kq + 2) * 36 + row] = a2;
    lds_a[(kq + 3) * 36 + row] = a3;
    __syncthreads();
    int kmax = K - k0;
    if (kmax > 32) kmax = 32;
    if (kmax == 32) {
#pragma unroll
      for (int kk = 0; kk < 32; ++kk) {
        float w = W[(size_t)(k0 + kk) * Cout + co];
        const float* ar = &lds_a[kk * 36 + rg * 8];
        float4 x0 = *(const float4*)ar;
        float4 x1 = *(const float4*)(ar + 4);
        acc[0] += x0.x * w; acc[1] += x0.y * w; acc[2] += x0.z * w; acc[3] += x0.w * w;
        acc[4] += x1.x * w; acc[5] += x1.y * w; acc[6] += x1.z * w; acc[7] += x1.w * w;
      }
    } else {
      for (int kk = 0; kk < kmax; ++kk) {
        float w = W[(size_t)(k0 + kk) * Cout + co];
        const float* ar = &lds_a[kk * 36 + rg * 8];
        float4 x0 = *(const float4*)ar;
        float4 x1 = *(const float4*)(ar + 4);
        acc[0] += x0.x * w; acc[1] += x0.y * w; acc[2] += x0.z * w; acc[3] += x0.w * w;
        acc[4] += x1.x * w; acc[5] += x1.y * w; acc[6] += x1.z * w; acc[7] += x1.w * w;
      }
    }
  }
  float bb = bias ? bias[co] : 0.0f;
#pragma unroll
  for (int j = 0; j < 8; ++j) {
    int r = r0 + rg * 8 + j;
    float vv = acc[j] + bb;
    if (relu) vv = fmaxf(vv, 0.0f);
    out[(size_t)r * Cout + co] = vv;
  }
}

__global__ __launch_bounds__(256) void gemm_kernel(const float* __restrict__ Amat,
                                                   const float* __restrict__ W,
                                                   const float* __restrict__ bias,
                                                   float* __restrict__ out, int K, int Cout,
                                                   int relu) {
  __shared__ float lds_a[32 * 36];
  gemm_body(blockIdx.x, blockIdx.y, Amat, W, bias, out, K, Cout, relu, lds_a);
}

__global__ __launch_bounds__(256) void gemm_qkv_kernel(
    const float* __restrict__ Amat, const float* __restrict__ Wq,
    const float* __restrict__ Wk, const float* __restrict__ Wv, float* __restrict__ oq,
    float* __restrict__ ok, float* __restrict__ ov, int K, int Cout) {
  __shared__ float lds_a[32 * 36];
  const float* W = blockIdx.z == 0 ? Wq : (blockIdx.z == 1 ? Wk : Wv);
  float* o = blockIdx.z == 0 ? oq : (blockIdx.z == 1 ? ok : ov);
  gemm_body(blockIdx.x, blockIdx.y, Amat, W, nullptr, o, K, Cout, 0, lds_a);
}

// interp-add: Y[r][c] += sum_j w3[r][j] * Zb[i3[r][j]][c]
__global__ __launch_bounds__(256) void interp_add_kernel(float* __restrict__ Y,
                                                         const int* __restrict__ i3,
                                                         const float* __restrict__ w3,
                                                         const float* __restrict__ Zb,
                                                         int Nd, int Ns, int C, int total) {
  int gid = blockIdx.x * 256 + threadIdx.x;
  if (gid >= total) return;
  int c = gid % C;
  int r = gid / C;
  int b = r / Nd;
  const int* ii = i3 + (size_t)r * 3;
  const float* ww = w3 + (size_t)r * 3;
  const float* zb = Zb + (size_t)b * Ns * C;
  Y[gid] += ww[0] * zb[(size_t)ii[0] * C + c] + ww[1] * zb[(size_t)ii[1] * C + c] +
            ww[2] * zb[(size_t)ii[2] * C + c];
}

// ---------------------------------------------------------------------------
// Combined launches (fps blocks FIRST so they are resident from t=0).
// ---------------------------------------------------------------------------
// A: fps 4096->512 (4 blocks) || knn_gw0 (4096 blocks x 4 queries)
__global__ __launch_bounds__(256) void combo_A_kernel(
    const float4* __restrict__ xw0, float r2, int* __restrict__ idxK0,
    const float* __restrict__ W0, const float* __restrict__ b0,
    const float* __restrict__ A0, float* __restrict__ fea0, int* __restrict__ idx1,
    float4* __restrict__ xw1) {
  __shared__ u64 smem[4160];
  if (blockIdx.x < NB) {
    fps_body<256, 16, 4096>(xw0, 4096, 512, idx1, xw1, smem, blockIdx.x, threadIdx.x);
  } else {
    int wave = threadIdx.x >> 6, lane = threadIdx.x & 63;
    int bn = (blockIdx.x - NB) * 4 + wave;
    knn_gw0_body(xw0, 4096, r2, idxK0, W0, b0, A0, fea0, bn, lane, smem + (size_t)wave * 1024,
                 smem + 4096 + wave * 16);
  }
}

// B: fps 512->128 (4) || knn_gw L1 (512 x 4 waves) || interp0 (64) || Y6a gemm (1024)
__global__ __launch_bounds__(256) void combo_B_kernel(
    const float4* __restrict__ xw0, const float4* __restrict__ xw1, float r2,
    int* __restrict__ idxK1, const int* __restrict__ idx1, const float* __restrict__ fea0,
    const float* __restrict__ A1, float* __restrict__ wf, int* __restrict__ idx2,
    float4* __restrict__ xw2, int* __restrict__ idxI0, float* __restrict__ wI0,
    const float* __restrict__ W6a, float* __restrict__ Y6) {
  __shared__ u64 smem[4160];
  int bid = blockIdx.x;
  if (bid < NB) {
    fps_body<256, 2, 512>(xw1, 512, 128, idx2, xw2, smem, bid, threadIdx.x);
  } else if (bid < NB + 512) {
    int wave = threadIdx.x >> 6, lane = threadIdx.x & 63;
    int bn = (bid - NB) * 4 + wave;
    knn_gw_body(xw1, 512, r2, idxK1, idx1, fea0, 4096, 64, A1, wf, bn, lane,
                smem + (size_t)wave * 1024, smem + 4096 + wave * 16);
  } else if (bid < NB + 512 + 64) {
    int gid = (bid - NB - 512) * 256 + threadIdx.x;
    interp3_body(xw0, xw1, 4096, 512, idxI0, wI0, gid);
  } else {
    int gb = bid - (NB + 512 + 64);
    gemm_body(gb & 1, gb >> 1, fea0, W6a, nullptr, Y6, 64, 128, 0, (float*)smem);
  }
}

// D: fps 128->64 (4) || knn_gw L2 (128 x 4 waves) || interp1 (8) || Y5a gemm (256)
__global__ __launch_bounds__(256) void combo_D_kernel(
    const float4* __restrict__ xw1, const float4* __restrict__ xw2, float r2,
    int* __restrict__ idxK2, const int* __restrict__ idx2, const float* __restrict__ fea1,
    const float* __restrict__ A2, float* __restrict__ wf, int* __restrict__ idx3,
    float4* __restrict__ xw3, int* __restrict__ idxI1, float* __restrict__ wI1,
    const float* __restrict__ W5a, float* __restrict__ Y5) {
  __shared__ u64 smem[4160];
  int bid = blockIdx.x;
  if (bid < NB) {
    fps_body<256, 1, 128>(xw2, 128, 64, idx3, xw3, smem, bid, threadIdx.x);
  } else if (bid < NB + 128) {
    int wave = threadIdx.x >> 6, lane = threadIdx.x & 63;
    int bn = (bid - NB) * 4 + wave;
    knn_gw_body(xw2, 128, r2, idxK2, idx2, fea1, 512, 128, A2, wf, bn, lane,
                smem + (size_t)wave * 1024, smem + 4096 + wave * 16);
  } else if (bid < NB + 128 + 8) {
    int gid = (bid - NB - 128) * 256 + threadIdx.x;
    interp3_body(xw1, xw2, 512, 128, idxI1, wI1, gid);
  } else {
    int gb = bid - (NB + 128 + 8);
    gemm_body(gb & 3, gb >> 2, fea1, W5a, nullptr, Y5, 128, 256, 0, (float*)smem);
  }
}

// H: knn_gw L3 (64 x 4 waves) || interp2 (2) || Y4a gemm (64)
__global__ __launch_bounds__(256) void combo_H_kernel(
    const float4* __restrict__ xw2, const float4* __restrict__ xw3, float r2,
    int* __restrict__ idxK3, const int* __restrict__ idx3, const float* __restrict__ fea2b,
    const float* __restrict__ A3, float* __restrict__ wf, int* __restrict__ idxI2,
    float* __restrict__ wI2, const float* __restrict__ W4a, float* __restrict__ Y4) {
  __shared__ u64 smem[4160];
  int bid = blockIdx.x;
  if (bid < 64) {
    int wave = threadIdx.x >> 6, lane = threadIdx.x & 63;
    int bn = bid * 4 + wave;
    knn_gw_body(xw3, 64, r2, idxK3, idx3, fea2b, 128, 256, A3, wf, bn, lane,
                smem + (size_t)wave * 1024, smem + 4096 + wave * 16);
  } else if (bid < 64 + 2) {
    int gid = (bid - 64) * 256 + threadIdx.x;
    interp3_body(xw2, xw3, 128, 64, idxI2, wI2, gid);
  } else {
    int gb = bid - 66;
    gemm_body(gb & 3, gb >> 2, fea2b, W4a, nullptr, Y4, 256, 256, 0, (float*)smem);
  }
}

// ---------------------------------------------------------------------------
// LAE gather-weight (POST-GEMM): out = relu(sum_k al_k Y[idx_k][c] + b[c])
// ---------------------------------------------------------------------------
__global__ __launch_bounds__(64) void gwpost_kernel(const float4* __restrict__ xw,
                                                    const float* __restrict__ Y,
                                                    const int* __restrict__ knn,
                                                    const float* __restrict__ A,
                                                    const float* __restrict__ bias,
                                                    float* __restrict__ out, int N, int C) {
  int bn = blockIdx.x;
  int b = bn / N, n = bn - b * N;
  int lane = threadIdx.x;
  const float4* xb = xw + (size_t)b * N;
  const int* kn = knn + (size_t)bn * 16;
  int idv[16];
#pragma unroll
  for (int k = 0; k < 16; ++k) idv[k] = kn[k];
  float al[16];
  lae_alphas(xb, n, idv, A, al);
  const float* Yb = Y + (size_t)b * N * C;
  float* wo = out + (size_t)bn * C;
  for (int c = lane; c < C; c += 64) {
    float acc = 0.0f;
#pragma unroll
    for (int k = 0; k < 16; ++k) acc += al[k] * Yb[(size_t)idv[k] * C + c];
    wo[c] = fmaxf(acc + bias[c], 0.0f);
  }
}

// L6 gwpost fused with final classifier (C=128 fixed), out (B,13,N)
__global__ __launch_bounds__(64) void gwpost_final_kernel(
    const float4* __restrict__ xw, const float* __restrict__ Y, const int* __restrict__ knn,
    const float* __restrict__ A, const float* __restrict__ bias,
    const float* __restrict__ Wf, const float* __restrict__ bfv, float* __restrict__ out,
    int N) {
  int bn = blockIdx.x;
  int b = bn / N, n = bn - b * N;
  int lane = threadIdx.x;
  const float4* xb = xw + (size_t)b * N;
  const int* kn = knn + (size_t)bn * 16;
  int idv[16];
#pragma unroll
  for (int k = 0; k < 16; ++k) idv[k] = kn[k];
  float al[16];
  lae_alphas(xb, n, idv, A, al);
  const float* Yb = Y + (size_t)b * N * 128;
  float a0 = 0.0f, a1 = 0.0f;
#pragma unroll
  for (int k = 0; k < 16; ++k) {
    const float* yr = Yb + (size_t)idv[k] * 128;
    a0 += al[k] * yr[lane];
    a1 += al[k] * yr[lane + 64];
  }
  float v0 = fmaxf(a0 + bias[lane], 0.0f);
  float v1 = fmaxf(a1 + bias[lane + 64], 0.0f);
  float* ob = out + ((size_t)b * 13) * N + n;
#pragma unroll
  for (int cls = 0; cls < 13; ++cls) {
    float p = v0 * Wf[lane * 13 + cls] + v1 * Wf[(lane + 64) * 13 + cls];
#pragma unroll
    for (int m = 32; m; m >>= 1) p += __shfl_xor(p, m);
    if (lane == 0) ob[(size_t)cls * N] = p + bfv[cls];
  }
}

// ---------------------------------------------------------------------------
// Self-attention mix: out[n] = softmax(q[n]·k^T) @ v + fea[n]. Block per (b,n).
// ---------------------------------------------------------------------------
__global__ __launch_bounds__(128) void attn_kernel(const float* __restrict__ q,
                                                   const float* __restrict__ k,
                                                   const float* __restrict__ v,
                                                   const float* __restrict__ fea,
                                                   float* __restrict__ out, int N, int C) {
  __shared__ float sa[128];
  __shared__ float sb[128];
  int b = blockIdx.y, n = blockIdx.x, t = threadIdx.x;
  const float* qn = q + ((size_t)b * N + n) * C;
  if (t < N) {
    const float4* km = (const float4*)(k + ((size_t)b * N + t) * C);
    const float4* q4 = (const float4*)qn;
    float acc = 0.0f;
    int C4 = C >> 2;
    for (int c = 0; c < C4; ++c) {
      float4 kv = km[c];
      float4 qv = q4[c];
      acc += qv.x * kv.x + qv.y * kv.y + qv.z * kv.z + qv.w * kv.w;
    }
    sa[t] = acc;
  }
  __syncthreads();
  float mx = -3.0e38f;
  for (int i = 0; i < N; ++i) mx = fmaxf(mx, sa[i]);
  if (t < N) sb[t] = expf(sa[t] - mx);
  __syncthreads();
  float sum = 0.0f;
  for (int i = 0; i < N; ++i) sum += sb[i];
  size_t rowo = ((size_t)b * N + n) * C;
  for (int c = t; c < C; c += 128) {
    float acc = 0.0f;
    for (int m = 0; m < N; ++m) acc += sb[m] * v[((size_t)b * N + m) * C + c];
    out[rowo + c] = acc / sum + fea[rowo + c];
  }
}

// ---------------------------------------------------------------------------
extern "C" void kernel_launch(void* const* d_in, const int* in_sizes, int n_in,
                              void* d_out, int out_size, void* d_ws, size_t ws_size,
                              hipStream_t stream) {
  (void)in_sizes; (void)n_in; (void)out_size; (void)ws_size;
  const float* xyz = (const float*)d_in[0];
  const float* W[7]; const float* bi[7]; const float* A[7];
  for (int i = 0; i < 7; ++i) {
    W[i] = (const float*)d_in[1 + 3 * i];
    bi[i] = (const float*)d_in[2 + 3 * i];
    A[i] = (const float*)d_in[3 + 3 * i];
  }
  const float* Wq1 = (const float*)d_in[22];
  const float* Wk1 = (const float*)d_in[23];
  const float* Wv1 = (const float*)d_in[24];
  const float* Wq2 = (const float*)d_in[25];
  const float* Wk2 = (const float*)d_in[26];
  const float* Wv2 = (const float*)d_in[27];
  const float* Wq3 = (const float*)d_in[28];
  const float* Wk3 = (const float*)d_in[29];
  const float* Wv3 = (const float*)d_in[30];
  const float* Wf = (const float*)d_in[31];
  const float* bf = (const float*)d_in[32];
  float* out = (float*)d_out;

  const int B = NB, N0 = 4096, N1 = 512, N2 = 128, N3 = 64;
  char* base = (char*)d_ws;
  size_t off = 0;
  auto alloc = [&](size_t bytes) -> void* {
    void* p = base + off;
    off += (bytes + 255) & ~(size_t)255;
    return p;
  };
  float4* xw0 = (float4*)alloc((size_t)B * N0 * 16);
  float4* xw1 = (float4*)alloc((size_t)B * N1 * 16);
  float4* xw2 = (float4*)alloc((size_t)B * N2 * 16);
  float4* xw3 = (float4*)alloc((size_t)B * N3 * 16);
  int* idxK0 = (int*)alloc((size_t)B * N0 * 16 * 4);
  int* idxK1 = (int*)alloc((size_t)B * N1 * 16 * 4);
  int* idxK2 = (int*)alloc((size_t)B * N2 * 16 * 4);
  int* idxK3 = (int*)alloc((size_t)B * N3 * 16 * 4);
  int* idx1 = (int*)alloc((size_t)B * N1 * 4);
  int* idx2 = (int*)alloc((size_t)B * N2 * 4);
  int* idx3 = (int*)alloc((size_t)B * N3 * 4);
  float* fea0 = (float*)alloc((size_t)B * N0 * 64 * 4);
  float* fea1 = (float*)alloc((size_t)B * N1 * 128 * 4);
  float* fea1b = (float*)alloc((size_t)B * N1 * 256 * 4);
  float* fea2a = (float*)alloc((size_t)B * N2 * 256 * 4);
  float* fea2b = (float*)alloc((size_t)B * N2 * 256 * 4);
  float* fea2c = (float*)alloc((size_t)B * N2 * 256 * 4);
  float* fea2d = (float*)alloc((size_t)B * N2 * 256 * 4);
  float* fea3a = (float*)alloc((size_t)B * N3 * 512 * 4);
  float* fea3b = (float*)alloc((size_t)B * N3 * 512 * 4);
  float* qb = (float*)alloc((size_t)B * 32768 * 4);
  float* kb = (float*)alloc((size_t)B * 32768 * 4);
  float* vb = (float*)alloc((size_t)B * 32768 * 4);
  int* idxI2 = (int*)alloc((size_t)B * N2 * 3 * 4);
  float* wI2 = (float*)alloc((size_t)B * N2 * 3 * 4);
  int* idxI1 = (int*)alloc((size_t)B * N1 * 3 * 4);
  float* wI1 = (float*)alloc((size_t)B * N1 * 3 * 4);
  int* idxI0 = (int*)alloc((size_t)B * N0 * 3 * 4);
  float* wI0 = (float*)alloc((size_t)B * N0 * 3 * 4);
  float* Zb4 = (float*)alloc((size_t)B * N3 * 256 * 4);
  float* Zb5 = (float*)alloc((size_t)B * N2 * 256 * 4);
  float* Zb6 = (float*)alloc((size_t)B * N1 * 128 * 4);
  float* Y4 = (float*)alloc((size_t)B * N2 * 256 * 4);
  float* Y5 = (float*)alloc((size_t)B * N1 * 256 * 4);
  float* Y6 = (float*)alloc((size_t)B * N0 * 128 * 4);
  float* wfb = (float*)alloc((size_t)B * N0 * 320 * 4);

  float r2_0 = (float)(0.06 * 0.06);
  float r2_1 = (float)(0.12 * 0.12);
  float r2_2 = (float)(0.3 * 0.3);
  float r2_3 = (float)(0.5 * 0.5);

  // 0: pack coords + norms
  norms_kernel<<<B * N0 / 256, 256, 0, stream>>>(xyz, xw0, B * N0);

  // A: fps(4096->512) || L0 knn+gw+gemm
  combo_A_kernel<<<B + B * N0 / 4, 256, 0, stream>>>(xw0, r2_0, idxK0, W[0], bi[0], A[0],
                                                     fea0, idx1, xw1);
  // B: fps(512->128) || L1 knn+gw || interp0 || Y6a = fea0@W6a
  combo_B_kernel<<<NB + 512 + 64 + 1024, 256, 0, stream>>>(
      xw0, xw1, r2_1, idxK1, idx1, fea0, A[1], wfb, idx2, xw2, idxI0, wI0, W[6], Y6);
  // C: gemm L1 -> fea1
  gemm_kernel<<<dim3(2, B * N1 / 32), 256, 0, stream>>>(wfb, W[1], bi[1], fea1, 64, 128, 1);
  // D: fps(128->64) || L2 knn+gw || interp1 || Y5a = fea1@W5a
  combo_D_kernel<<<NB + 128 + 8 + 256, 256, 0, stream>>>(
      xw1, xw2, r2_2, idxK2, idx2, fea1, A[2], wfb, idx3, xw3, idxI1, wI1, W[5], Y5);
  // E: gemm L2 -> fea2a; qkv1; attn1 -> fea2b
  gemm_kernel<<<dim3(4, B * N2 / 32), 256, 0, stream>>>(wfb, W[2], bi[2], fea2a, 128, 256, 1);
  gemm_qkv_kernel<<<dim3(4, B * N2 / 32, 3), 256, 0, stream>>>(fea2a, Wq1, Wk1, Wv1, qb, kb,
                                                               vb, 256, 256);
  attn_kernel<<<dim3(N2, B), 128, 0, stream>>>(qb, kb, vb, fea2a, fea2b, N2, 256);

  // H: L3 knn+gw || interp2 || Y4a = fea2b@W4a
  combo_H_kernel<<<64 + 2 + 64, 256, 0, stream>>>(xw2, xw3, r2_3, idxK3, idx3, fea2b, A[3],
                                                  wfb, idxI2, wI2, W[4], Y4);
  // I: gemm L3 -> fea3a; qkv2; attn2 -> fea3b
  gemm_kernel<<<dim3(8, B * N3 / 32), 256, 0, stream>>>(wfb, W[3], bi[3], fea3a, 256, 512, 1);
  gemm_qkv_kernel<<<dim3(8, B * N3 / 32, 3), 256, 0, stream>>>(fea3a, Wq2, Wk2, Wv2, qb, kb,
                                                               vb, 512, 512);
  attn_kernel<<<dim3(N3, B), 128, 0, stream>>>(qb, kb, vb, fea3a, fea3b, N3, 512);

  // L4: Zb4 = fea3b@W4b; Y4 += interp(Zb4); gwpost -> fea2c; qkv3; attn3
  gemm_kernel<<<dim3(4, B * N3 / 32), 256, 0, stream>>>(fea3b, W[4] + 256 * 256, nullptr, Zb4,
                                                        512, 256, 0);
  interp_add_kernel<<<B * N2 * 256 / 256, 256, 0, stream>>>(Y4, idxI2, wI2, Zb4, N2, N3, 256,
                                                            B * N2 * 256);
  gwpost_kernel<<<B * N2, 64, 0, stream>>>(xw2, Y4, idxK2, A[4], bi[4], fea2c, N2, 256);
  gemm_qkv_kernel<<<dim3(4, B * N2 / 32, 3), 256, 0, stream>>>(fea2c, Wq3, Wk3, Wv3, qb, kb,
                                                               vb, 256, 256);
  attn_kernel<<<dim3(N2, B), 128, 0, stream>>>(qb, kb, vb, fea2c, fea2d, N2, 256);

  // L5: Zb5 = fea2d@W5b; Y5 += interp(Zb5); gwpost -> fea1b
  gemm_kernel<<<dim3(4, B * N2 / 32), 256, 0, stream>>>(fea2d, W[5] + 128 * 256, nullptr, Zb5,
                                                        256, 256, 0);
  interp_add_kernel<<<B * N1 * 256 / 256, 256, 0, stream>>>(Y5, idxI1, wI1, Zb5, N1, N2, 256,
                                                            B * N1 * 256);
  gwpost_kernel<<<B * N1, 64, 0, stream>>>(xw1, Y5, idxK1, A[5], bi[5], fea1b, N1, 256);

  // L6: Zb6 = fea1b@W6b; Y6 += interp(Zb6); gwpost+final -> out
  gemm_kernel<<<dim3(2, B * N1 / 32), 256, 0, stream>>>(fea1b, W[6] + 64 * 128, nullptr, Zb6,
                                                        256, 128, 0);
  interp_add_kernel<<<B * N0 * 128 / 256, 256, 0, stream>>>(Y6, idxI0, wI0, Zb6, N0, N1, 128,
                                                            B * N0 * 128);
  gwpost_final_kernel<<<B * N0, 64, 0, stream>>>(xw0, Y6, idxK0, A[6], bi[6], Wf, bf, out,
                                                 N0);
}

// Round 12
// 860.916 us; speedup vs baseline: 4.6208x; 1.1914x over previous
//
#include <hip/hip_runtime.h>
#include <math.h>

#define NB 4  // batch

typedef unsigned long long u64;

// branchless ascending compare-swap on u64 keys
#define CSWAP(a, b)                                          \
  {                                                          \
    u64 _mn = (b < a) ? b : a;                               \
    u64 _mx = (b < a) ? a : b;                               \
    a = _mn;                                                 \
    b = _mx;                                                 \
  }

// ---------------------------------------------------------------------------
// Pack xyz (stride 3) -> xyzw float4 with norm (left-assoc, contract off:
// bit-identical to reference pdist2 norms).
// ---------------------------------------------------------------------------
__global__ __launch_bounds__(256) void norms_kernel(const float* __restrict__ xyz,
                                                    float4* __restrict__ xw, int total) {
#pragma clang fp contract(off)
  int i = blockIdx.x * 256 + threadIdx.x;
  if (i >= total) return;
  float x = xyz[3 * i + 0], y = xyz[3 * i + 1], z = xyz[3 * i + 2];
  xw[i] = make_float4(x, y, z, x * x + y * y + z * z);
}

// ---------------------------------------------------------------------------
// kNN-16 top-16 search (per-wave) on packed float4 coords. Key =
// (d2_bits<<32)|idx == exact (d2, idx) lexicographic order == stable top_k.
// ---------------------------------------------------------------------------
__device__ __forceinline__ void knn16_search(const float4* __restrict__ xwb, int N, int n,
                                             int lane, u64* lists, u64* win) {
#pragma clang fp contract(off)
  float4 q = xwb[n];
  float qq = q.w;
  const u64 SENT = ((u64)0x7F800000u << 32) | (unsigned)lane;
  u64 k0 = SENT, k1 = SENT, k2 = SENT, k3 = SENT, k4 = SENT, k5 = SENT, k6 = SENT,
      k7 = SENT, k8 = SENT, k9 = SENT, k10 = SENT, k11 = SENT, k12 = SENT, k13 = SENT,
      k14 = SENT, k15 = SENT;
  int rounds = N >> 6;
  for (int j = 0; j < rounds; ++j) {
    int m = j * 64 + lane;
    float4 p = xwb[m];
    float ab = q.x * p.x + q.y * p.y + q.z * p.z;
    float d2 = fmaxf((qq + p.w) - 2.0f * ab, 0.0f);
    u64 key = ((u64)__float_as_uint(d2) << 32) | (unsigned)m;
    if (key < k15) {
      k15 = key;
      CSWAP(k14, k15); CSWAP(k13, k14); CSWAP(k12, k13); CSWAP(k11, k12);
      CSWAP(k10, k11); CSWAP(k9, k10);  CSWAP(k8, k9);   CSWAP(k7, k8);
      CSWAP(k6, k7);   CSWAP(k5, k6);   CSWAP(k4, k5);   CSWAP(k3, k4);
      CSWAP(k2, k3);   CSWAP(k1, k2);   CSWAP(k0, k1);
    }
  }
  lists[0 * 64 + lane] = k0;   lists[1 * 64 + lane] = k1;
  lists[2 * 64 + lane] = k2;   lists[3 * 64 + lane] = k3;
  lists[4 * 64 + lane] = k4;   lists[5 * 64 + lane] = k5;
  lists[6 * 64 + lane] = k6;   lists[7 * 64 + lane] = k7;
  lists[8 * 64 + lane] = k8;   lists[9 * 64 + lane] = k9;
  lists[10 * 64 + lane] = k10; lists[11 * 64 + lane] = k11;
  lists[12 * 64 + lane] = k12; lists[13 * 64 + lane] = k13;
  lists[14 * 64 + lane] = k14; lists[15 * 64 + lane] = k15;
  __syncthreads();
  int head = 0;
  u64 outk = 0;
  for (int r = 0; r < 16; ++r) {
    u64 h = lists[head * 64 + lane];
    u64 mn = h;
#pragma unroll
    for (int mask = 32; mask; mask >>= 1) {
      u64 o = __shfl_xor(mn, mask);
      if (o < mn) mn = o;
    }
    if (h == mn) head++;
    if (lane == r) outk = mn;
  }
  if (lane < 16) win[lane] = outk;
  __syncthreads();
}

// softmax alphas over 16 neighbor coordinate offsets (all lanes redundant)
__device__ __forceinline__ void lae_alphas(const float4* __restrict__ xwb, int n,
                                           const int* idv, const float* __restrict__ A,
                                           float* al) {
  float ax = A[0], ay = A[1], az = A[2];
  float4 q = xwb[n];
  float mx = -3.0e38f;
#pragma unroll
  for (int k = 0; k < 16; ++k) {
    float4 p = xwb[idv[k]];
    float gx = p.x - q.x, gy = p.y - q.y, gz = p.z - q.z;
    float s = gx * ax + gy * ay + gz * az;
    al[k] = s;
    mx = fmaxf(mx, s);
  }
  float sum = 0.0f;
#pragma unroll
  for (int k = 0; k < 16; ++k) { al[k] = expf(al[k] - mx); sum += al[k]; }
#pragma unroll
  for (int k = 0; k < 16; ++k) al[k] = al[k] / sum;
}

// ---------------------------------------------------------------------------
// FPS body. Contiguous per-thread point chunks (pt = tid*PTS + p) so lane
// order == point order. Per-iter: dist update + local argmax (strict > keeps
// lowest p) -> f32 6-level shuffle max -> ballot+ffsll picks lowest tied lane
// -> shfl extracts its point idx -> cross-wave u64 (dist_bits<<32 | ~idx)
// compare (max dist, tie -> lowest idx). Exact jnp.argmax semantics.
// ---------------------------------------------------------------------------
template <int NT, int PTS, int NPT>
__device__ __forceinline__ void fps_body(const float4* __restrict__ xw, int N, int npoint,
                                         int* __restrict__ idx_out,
                                         float4* __restrict__ xw_out, u64* smem, int b,
                                         int tid) {
#pragma clang fp contract(off)
  constexpr int NW = NT / 64;
  constexpr bool FULL = (NT * PTS == NPT);
  u64* rk = smem;
  int* hist = (int*)(smem + 2 * NW);
  float* sxyz = (float*)(hist + 512);
  const float4* xb = xw + (size_t)b * N;
  for (int i = tid; i < N; i += NT) {
    float4 p = xb[i];
    sxyz[3 * i + 0] = p.x;
    sxyz[3 * i + 1] = p.y;
    sxyz[3 * i + 2] = p.z;
  }
  float px[PTS], py[PTS], pz[PTS], dist[PTS];
#pragma unroll
  for (int p = 0; p < PTS; ++p) {
    int pt = tid * PTS + p;
    if (FULL || pt < N) {
      float4 v = xb[pt];
      px[p] = v.x;
      py[p] = v.y;
      pz[p] = v.z;
    }
    dist[p] = 1e10f;
  }
  __syncthreads();
  int far = 0;
  float cx = sxyz[0], cy = sxyz[1], cz = sxyz[2];
  for (int t = 0; t < npoint; ++t) {
    if (tid == 0) hist[t] = far;
    float bestd = -1.0f;
    int bestp = 0;
#pragma unroll
    for (int p = 0; p < PTS; ++p) {
      int pt = tid * PTS + p;
      if (FULL || pt < N) {
        float dx = px[p] - cx, dy = py[p] - cy, dz = pz[p] - cz;
        float d = dx * dx + dy * dy + dz * dz;
        float nd = fminf(dist[p], d);
        dist[p] = nd;
        if (nd > bestd) { bestd = nd; bestp = pt; }  // ascending pt: keeps lowest
      }
    }
    float wmax = bestd;
#pragma unroll
    for (int m = 1; m <= 32; m <<= 1) wmax = fmaxf(wmax, __shfl_xor(wmax, m));
    u64 mask = __ballot(bestd == wmax);
    int wl = __ffsll(mask) - 1;
    int widx = __shfl(bestp, wl);
    u64 key = (wmax < 0.0f)
                  ? 0ull
                  : (((u64)__float_as_uint(wmax) << 32) | (unsigned)(~widx));
    if constexpr (NW > 1) {
      int par = (t & 1) * NW;
      if ((tid & 63) == 0) rk[par + (tid >> 6)] = key;
      __syncthreads();
      key = rk[par + 0];
#pragma unroll
      for (int w = 1; w < NW; ++w) {
        u64 o = rk[par + w];
        if (o > key) key = o;
      }
    }
    far = (int)(~(unsigned)key);
    cx = sxyz[3 * far + 0];
    cy = sxyz[3 * far + 1];
    cz = sxyz[3 * far + 2];
  }
  __syncthreads();
  for (int s = tid; s < npoint; s += NT) {
    int idp = hist[s];
    idx_out[(size_t)b * npoint + s] = idp;
    xw_out[(size_t)b * npoint + s] = xb[idp];
  }
}

// ---------------------------------------------------------------------------
// knn_gw body: kNN + ball filter + softmax-weighted feature sum with source
// row indirection. One wave per query.
// ---------------------------------------------------------------------------
__device__ __forceinline__ void knn_gw_body(const float4* __restrict__ xw_s, int N, float r2,
                                            int* __restrict__ idxK,
                                            const int* __restrict__ srcmap,
                                            const float* __restrict__ fea_src, int Nsrc,
                                            int Cin, const float* __restrict__ A,
                                            float* __restrict__ wf, int bn, int lane,
                                            u64* lists, u64* win) {
  int b = bn / N, n = bn - b * N;
  const float4* xb = xw_s + (size_t)b * N;
  knn16_search(xb, N, n, lane, lists, win);
  int idv[16];
#pragma unroll
  for (int k = 0; k < 16; ++k) {
    u64 kk = win[k];
    float d2 = __uint_as_float((unsigned)(kk >> 32));
    idv[k] = (d2 <= r2) ? (int)(kk & 0xFFFFFFFFu) : n;
  }
  if (lane < 16) idxK[(size_t)bn * 16 + lane] = idv[lane];
  float al[16];
  lae_alphas(xb, n, idv, A, al);
  int row[16];
  const int* sm = srcmap + (size_t)b * N;
#pragma unroll
  for (int k = 0; k < 16; ++k) row[k] = sm[idv[k]];
  const float* fb = fea_src + (size_t)b * Nsrc * Cin;
  float* wo = wf + (size_t)bn * Cin;
  for (int c = lane; c < Cin; c += 64) {
    float acc = 0.0f;
#pragma unroll
    for (int k = 0; k < 16; ++k) acc += al[k] * fb[(size_t)row[k] * Cin + c];
    wo[c] = acc;
  }
}

// L0 variant: fea == xyz (Cin=3) with fused K=3 mini-GEMM -> fea0 (Cout=64)
__device__ __forceinline__ void knn_gw0_body(const float4* __restrict__ xw, int N, float r2,
                                             int* __restrict__ idxK,
                                             const float* __restrict__ W0,
                                             const float* __restrict__ b0,
                                             const float* __restrict__ A0,
                                             float* __restrict__ fea0, int bn, int lane,
                                             u64* lists, u64* win) {
  int b = bn / N, n = bn - b * N;
  const float4* xb = xw + (size_t)b * N;
  knn16_search(xb, N, n, lane, lists, win);
  int idv[16];
#pragma unroll
  for (int k = 0; k < 16; ++k) {
    u64 kk = win[k];
    float d2 = __uint_as_float((unsigned)(kk >> 32));
    idv[k] = (d2 <= r2) ? (int)(kk & 0xFFFFFFFFu) : n;
  }
  if (lane < 16) idxK[(size_t)bn * 16 + lane] = idv[lane];
  float al[16];
  lae_alphas(xb, n, idv, A0, al);
  float w0 = 0.0f, w1 = 0.0f, w2 = 0.0f;
#pragma unroll
  for (int k = 0; k < 16; ++k) {
    float4 p = xb[idv[k]];
    w0 += al[k] * p.x;
    w1 += al[k] * p.y;
    w2 += al[k] * p.z;
  }
  float v = w0 * W0[0 * 64 + lane] + w1 * W0[1 * 64 + lane] + w2 * W0[2 * 64 + lane] +
            b0[lane];
  fea0[(size_t)bn * 64 + lane] = fmaxf(v, 0.0f);
}

// ---------------------------------------------------------------------------
// 3-NN inverse-distance body (pdist2 form, stable top-3), packed coords.
// ---------------------------------------------------------------------------
__device__ __forceinline__ void interp3_body(const float4* __restrict__ xd,
                                             const float4* __restrict__ xs, int Nd, int Ns,
                                             int* __restrict__ idx3, float* __restrict__ w3,
                                             int gid) {
#pragma clang fp contract(off)
  int b = gid / Nd;
  const float4* xb = xs + (size_t)b * Ns;
  float4 q = xd[gid];
  float qq = q.w;
  float v0 = 3.0e38f, v1 = 3.0e38f, v2 = 3.0e38f;
  int i0 = 0, i1 = 0, i2 = 0;
  for (int m = 0; m < Ns; ++m) {
    float4 p = xb[m];
    float ab = q.x * p.x + q.y * p.y + q.z * p.z;
    float d2 = fmaxf((qq + p.w) - 2.0f * ab, 0.0f);
    if (d2 < v2) {
      if (d2 < v0) { v2 = v1; i2 = i1; v1 = v0; i1 = i0; v0 = d2; i0 = m; }
      else if (d2 < v1) { v2 = v1; i2 = i1; v1 = d2; i1 = m; }
      else { v2 = d2; i2 = m; }
    }
  }
  float w0 = 1.0f / fmaxf(v0, 1e-10f);
  float w1 = 1.0f / fmaxf(v1, 1e-10f);
  float w2 = 1.0f / fmaxf(v2, 1e-10f);
  float s = w0 + w1 + w2;
  idx3[gid * 3 + 0] = i0; idx3[gid * 3 + 1] = i1; idx3[gid * 3 + 2] = i2;
  w3[gid * 3 + 0] = w0 / s; w3[gid * 3 + 1] = w1 / s; w3[gid * 3 + 2] = w2 / s;
}

// ---------------------------------------------------------------------------
// Tiled fp32 GEMM body (tile bx, by given explicitly so combos can pack it).
// Block 256 = 64 couts x 4 row-groups; tile 32 rows x 64 couts.
// ---------------------------------------------------------------------------
__device__ __forceinline__ void gemm_body(int bx, int by, const float* __restrict__ Amat,
                                          const float* __restrict__ W,
                                          const float* __restrict__ bias,
                                          float* __restrict__ out, int K, int Cout, int relu,
                                          float* lds_a) {
  int co = bx * 64 + (threadIdx.x & 63);
  int rg = threadIdx.x >> 6;
  int r0 = by * 32;
  float acc[8];
#pragma unroll
  for (int j = 0; j < 8; ++j) acc[j] = 0.0f;
  for (int k0 = 0; k0 < K; k0 += 32) {
    int row = threadIdx.x >> 3;
    int kq = (threadIdx.x & 7) * 4;
    int gk = k0 + kq;
    const float* ap = Amat + (size_t)(r0 + row) * K + gk;
    float a0 = 0.0f, a1 = 0.0f, a2 = 0.0f, a3 = 0.0f;
    if (gk + 3 < K) {
      float4 tv = *(const float4*)ap;
      a0 = tv.x; a1 = tv.y; a2 = tv.z; a3 = tv.w;
    } else {
      if (gk + 0 < K) a0 = ap[0];
      if (gk + 1 < K) a1 = ap[1];
      if (gk + 2 < K) a2 = ap[2];
    }
    __syncthreads();
    lds_a[(kq + 0) * 36 + row] = a0;
    lds_a[(kq + 1) * 36 + row] = a1;
    lds_a[(kq + 2) * 36 + row] = a2;
    lds_a[(kq + 3) * 36 + row] = a3;
    __syncthreads();
    int kmax = K - k0;
    if (kmax > 32) kmax = 32;
    if (kmax == 32) {
#pragma unroll
      for (int kk = 0; kk < 32; ++kk) {
        float w = W[(size_t)(k0 + kk) * Cout + co];
        const float* ar = &lds_a[kk * 36 + rg * 8];
        float4 x0 = *(const float4*)ar;
        float4 x1 = *(const float4*)(ar + 4);
        acc[0] += x0.x * w; acc[1] += x0.y * w; acc[2] += x0.z * w; acc[3] += x0.w * w;
        acc[4] += x1.x * w; acc[5] += x1.y * w; acc[6] += x1.z * w; acc[7] += x1.w * w;
      }
    } else {
      for (int kk = 0; kk < kmax; ++kk) {
        float w = W[(size_t)(k0 + kk) * Cout + co];
        const float* ar = &lds_a[kk * 36 + rg * 8];
        float4 x0 = *(const float4*)ar;
        float4 x1 = *(const float4*)(ar + 4);
        acc[0] += x0.x * w; acc[1] += x0.y * w; acc[2] += x0.z * w; acc[3] += x0.w * w;
        acc[4] += x1.x * w; acc[5] += x1.y * w; acc[6] += x1.z * w; acc[7] += x1.w * w;
      }
    }
  }
  float bb = bias ? bias[co] : 0.0f;
#pragma unroll
  for (int j = 0; j < 8; ++j) {
    int r = r0 + rg * 8 + j;
    float vv = acc[j] + bb;
    if (relu) vv = fmaxf(vv, 0.0f);
    out[(size_t)r * Cout + co] = vv;
  }
}

__global__ __launch_bounds__(256) void gemm_kernel(const float* __restrict__ Amat,
                                                   const float* __restrict__ W,
                                                   const float* __restrict__ bias,
                                                   float* __restrict__ out, int K, int Cout,
                                                   int relu) {
  __shared__ float lds_a[32 * 36];
  gemm_body(blockIdx.x, blockIdx.y, Amat, W, bias, out, K, Cout, relu, lds_a);
}

__global__ __launch_bounds__(256) void gemm_qkv_kernel(
    const float* __restrict__ Amat, const float* __restrict__ Wq,
    const float* __restrict__ Wk, const float* __restrict__ Wv, float* __restrict__ oq,
    float* __restrict__ ok, float* __restrict__ ov, int K, int Cout) {
  __shared__ float lds_a[32 * 36];
  const float* W = blockIdx.z == 0 ? Wq : (blockIdx.z == 1 ? Wk : Wv);
  float* o = blockIdx.z == 0 ? oq : (blockIdx.z == 1 ? ok : ov);
  gemm_body(blockIdx.x, blockIdx.y, Amat, W, nullptr, o, K, Cout, 0, lds_a);
}

// interp-add: Y[r][c] += sum_j w3[r][j] * Zb[i3[r][j]][c]  (bit-identical to
// the old fused GEMM epilogue decomposition)
__global__ __launch_bounds__(256) void interp_add_kernel(float* __restrict__ Y,
                                                         const int* __restrict__ i3,
                                                         const float* __restrict__ w3,
                                                         const float* __restrict__ Zb,
                                                         int Nd, int Ns, int C, int total) {
  int gid = blockIdx.x * 256 + threadIdx.x;
  if (gid >= total) return;
  int c = gid % C;
  int r = gid / C;
  int b = r / Nd;
  const int* ii = i3 + (size_t)r * 3;
  const float* ww = w3 + (size_t)r * 3;
  const float* zb = Zb + (size_t)b * Ns * C;
  Y[gid] += ww[0] * zb[(size_t)ii[0] * C + c] + ww[1] * zb[(size_t)ii[1] * C + c] +
            ww[2] * zb[(size_t)ii[2] * C + c];
}

// ---------------------------------------------------------------------------
// Combined launches (fps blocks FIRST so they are resident from t=0).
// ---------------------------------------------------------------------------
// A: fps 4096->512 (4 blocks) || knn_gw0 (4096 blocks x 4 queries)
__global__ __launch_bounds__(256) void combo_A_kernel(
    const float4* __restrict__ xw0, float r2, int* __restrict__ idxK0,
    const float* __restrict__ W0, const float* __restrict__ b0,
    const float* __restrict__ A0, float* __restrict__ fea0, int* __restrict__ idx1,
    float4* __restrict__ xw1) {
  __shared__ u64 smem[6432];
  if (blockIdx.x < NB) {
    fps_body<256, 16, 4096>(xw0, 4096, 512, idx1, xw1, smem, blockIdx.x, threadIdx.x);
  } else {
    int wave = threadIdx.x >> 6, lane = threadIdx.x & 63;
    int bn = (blockIdx.x - NB) * 4 + wave;
    knn_gw0_body(xw0, 4096, r2, idxK0, W0, b0, A0, fea0, bn, lane, smem + (size_t)wave * 1024,
                 smem + 4096 + wave * 16);
  }
}

// B: fps 512->128 (4) || knn_gw L1 (512 x 4 waves) || interp0 (64) || Y6a gemm (1024)
__global__ __launch_bounds__(256) void combo_B_kernel(
    const float4* __restrict__ xw0, const float4* __restrict__ xw1, float r2,
    int* __restrict__ idxK1, const int* __restrict__ idx1, const float* __restrict__ fea0,
    const float* __restrict__ A1, float* __restrict__ wf, int* __restrict__ idx2,
    float4* __restrict__ xw2, int* __restrict__ idxI0, float* __restrict__ wI0,
    const float* __restrict__ W6a, float* __restrict__ Y6) {
  __shared__ u64 smem[4160];
  int bid = blockIdx.x;
  if (bid < NB) {
    fps_body<256, 2, 512>(xw1, 512, 128, idx2, xw2, smem, bid, threadIdx.x);
  } else if (bid < NB + 512) {
    int wave = threadIdx.x >> 6, lane = threadIdx.x & 63;
    int bn = (bid - NB) * 4 + wave;
    knn_gw_body(xw1, 512, r2, idxK1, idx1, fea0, 4096, 64, A1, wf, bn, lane,
                smem + (size_t)wave * 1024, smem + 4096 + wave * 16);
  } else if (bid < NB + 512 + 64) {
    int gid = (bid - NB - 512) * 256 + threadIdx.x;
    interp3_body(xw0, xw1, 4096, 512, idxI0, wI0, gid);
  } else {
    int gb = bid - (NB + 512 + 64);
    gemm_body(gb & 1, gb >> 1, fea0, W6a, nullptr, Y6, 64, 128, 0, (float*)smem);
  }
}

// D: fps 128->64 (4) || knn_gw L2 (128 x 4 waves) || interp1 (8) || Y5a gemm (256)
__global__ __launch_bounds__(256) void combo_D_kernel(
    const float4* __restrict__ xw1, const float4* __restrict__ xw2, float r2,
    int* __restrict__ idxK2, const int* __restrict__ idx2, const float* __restrict__ fea1,
    const float* __restrict__ A2, float* __restrict__ wf, int* __restrict__ idx3,
    float4* __restrict__ xw3, int* __restrict__ idxI1, float* __restrict__ wI1,
    const float* __restrict__ W5a, float* __restrict__ Y5) {
  __shared__ u64 smem[4160];
  int bid = blockIdx.x;
  if (bid < NB) {
    fps_body<256, 1, 128>(xw2, 128, 64, idx3, xw3, smem, bid, threadIdx.x);
  } else if (bid < NB + 128) {
    int wave = threadIdx.x >> 6, lane = threadIdx.x & 63;
    int bn = (bid - NB) * 4 + wave;
    knn_gw_body(xw2, 128, r2, idxK2, idx2, fea1, 512, 128, A2, wf, bn, lane,
                smem + (size_t)wave * 1024, smem + 4096 + wave * 16);
  } else if (bid < NB + 128 + 8) {
    int gid = (bid - NB - 128) * 256 + threadIdx.x;
    interp3_body(xw1, xw2, 512, 128, idxI1, wI1, gid);
  } else {
    int gb = bid - (NB + 128 + 8);
    gemm_body(gb & 3, gb >> 2, fea1, W5a, nullptr, Y5, 128, 256, 0, (float*)smem);
  }
}

// H: knn_gw L3 (64 x 4 waves) || interp2 (2) || Y4a gemm (64)
__global__ __launch_bounds__(256) void combo_H_kernel(
    const float4* __restrict__ xw2, const float4* __restrict__ xw3, float r2,
    int* __restrict__ idxK3, const int* __restrict__ idx3, const float* __restrict__ fea2b,
    const float* __restrict__ A3, float* __restrict__ wf, int* __restrict__ idxI2,
    float* __restrict__ wI2, const float* __restrict__ W4a, float* __restrict__ Y4) {
  __shared__ u64 smem[4160];
  int bid = blockIdx.x;
  if (bid < 64) {
    int wave = threadIdx.x >> 6, lane = threadIdx.x & 63;
    int bn = bid * 4 + wave;
    knn_gw_body(xw3, 64, r2, idxK3, idx3, fea2b, 128, 256, A3, wf, bn, lane,
                smem + (size_t)wave * 1024, smem + 4096 + wave * 16);
  } else if (bid < 64 + 2) {
    int gid = (bid - 64) * 256 + threadIdx.x;
    interp3_body(xw2, xw3, 128, 64, idxI2, wI2, gid);
  } else {
    int gb = bid - 66;
    gemm_body(gb & 3, gb >> 2, fea2b, W4a, nullptr, Y4, 256, 256, 0, (float*)smem);
  }
}

// ---------------------------------------------------------------------------
// LAE gather-weight (POST-GEMM): out = relu(sum_k al_k Y[idx_k][c] + b[c])
// ---------------------------------------------------------------------------
__global__ __launch_bounds__(64) void gwpost_kernel(const float4* __restrict__ xw,
                                                    const float* __restrict__ Y,
                                                    const int* __restrict__ knn,
                                                    const float* __restrict__ A,
                                                    const float* __restrict__ bias,
                                                    float* __restrict__ out, int N, int C) {
  int bn = blockIdx.x;
  int b = bn / N, n = bn - b * N;
  int lane = threadIdx.x;
  const float4* xb = xw + (size_t)b * N;
  const int* kn = knn + (size_t)bn * 16;
  int idv[16];
#pragma unroll
  for (int k = 0; k < 16; ++k) idv[k] = kn[k];
  float al[16];
  lae_alphas(xb, n, idv, A, al);
  const float* Yb = Y + (size_t)b * N * C;
  float* wo = out + (size_t)bn * C;
  for (int c = lane; c < C; c += 64) {
    float acc = 0.0f;
#pragma unroll
    for (int k = 0; k < 16; ++k) acc += al[k] * Yb[(size_t)idv[k] * C + c];
    wo[c] = fmaxf(acc + bias[c], 0.0f);
  }
}

// L6 gwpost fused with final classifier (C=128 fixed), out (B,13,N)
__global__ __launch_bounds__(64) void gwpost_final_kernel(
    const float4* __restrict__ xw, const float* __restrict__ Y, const int* __restrict__ knn,
    const float* __restrict__ A, const float* __restrict__ bias,
    const float* __restrict__ Wf, const float* __restrict__ bfv, float* __restrict__ out,
    int N) {
  int bn = blockIdx.x;
  int b = bn / N, n = bn - b * N;
  int lane = threadIdx.x;
  const float4* xb = xw + (size_t)b * N;
  const int* kn = knn + (size_t)bn * 16;
  int idv[16];
#pragma unroll
  for (int k = 0; k < 16; ++k) idv[k] = kn[k];
  float al[16];
  lae_alphas(xb, n, idv, A, al);
  const float* Yb = Y + (size_t)b * N * 128;
  float a0 = 0.0f, a1 = 0.0f;
#pragma unroll
  for (int k = 0; k < 16; ++k) {
    const float* yr = Yb + (size_t)idv[k] * 128;
    a0 += al[k] * yr[lane];
    a1 += al[k] * yr[lane + 64];
  }
  float v0 = fmaxf(a0 + bias[lane], 0.0f);
  float v1 = fmaxf(a1 + bias[lane + 64], 0.0f);
  float* ob = out + ((size_t)b * 13) * N + n;
#pragma unroll
  for (int cls = 0; cls < 13; ++cls) {
    float p = v0 * Wf[lane * 13 + cls] + v1 * Wf[(lane + 64) * 13 + cls];
#pragma unroll
    for (int m = 32; m; m >>= 1) p += __shfl_xor(p, m);
    if (lane == 0) ob[(size_t)cls * N] = p + bfv[cls];
  }
}

// ---------------------------------------------------------------------------
// Self-attention mix: out[n] = softmax(q[n]·k^T) @ v + fea[n]. Block per (b,n).
// ---------------------------------------------------------------------------
__global__ __launch_bounds__(128) void attn_kernel(const float* __restrict__ q,
                                                   const float* __restrict__ k,
                                                   const float* __restrict__ v,
                                                   const float* __restrict__ fea,
                                                   float* __restrict__ out, int N, int C) {
  __shared__ float sa[128];
  __shared__ float sb[128];
  int b = blockIdx.y, n = blockIdx.x, t = threadIdx.x;
  const float* qn = q + ((size_t)b * N + n) * C;
  if (t < N) {
    const float4* km = (const float4*)(k + ((size_t)b * N + t) * C);
    const float4* q4 = (const float4*)qn;
    float acc = 0.0f;
    int C4 = C >> 2;
    for (int c = 0; c < C4; ++c) {
      float4 kv = km[c];
      float4 qv = q4[c];
      acc += qv.x * kv.x + qv.y * kv.y + qv.z * kv.z + qv.w * kv.w;
    }
    sa[t] = acc;
  }
  __syncthreads();
  float mx = -3.0e38f;
  for (int i = 0; i < N; ++i) mx = fmaxf(mx, sa[i]);
  if (t < N) sb[t] = expf(sa[t] - mx);
  __syncthreads();
  float sum = 0.0f;
  for (int i = 0; i < N; ++i) sum += sb[i];
  size_t rowo = ((size_t)b * N + n) * C;
  for (int c = t; c < C; c += 128) {
    float acc = 0.0f;
    for (int m = 0; m < N; ++m) acc += sb[m] * v[((size_t)b * N + m) * C + c];
    out[rowo + c] = acc / sum + fea[rowo + c];
  }
}

// ---------------------------------------------------------------------------
extern "C" void kernel_launch(void* const* d_in, const int* in_sizes, int n_in,
                              void* d_out, int out_size, void* d_ws, size_t ws_size,
                              hipStream_t stream) {
  (void)in_sizes; (void)n_in; (void)out_size; (void)ws_size;
  const float* xyz = (const float*)d_in[0];
  const float* W[7]; const float* bi[7]; const float* A[7];
  for (int i = 0; i < 7; ++i) {
    W[i] = (const float*)d_in[1 + 3 * i];
    bi[i] = (const float*)d_in[2 + 3 * i];
    A[i] = (const float*)d_in[3 + 3 * i];
  }
  const float* Wq1 = (const float*)d_in[22];
  const float* Wk1 = (const float*)d_in[23];
  const float* Wv1 = (const float*)d_in[24];
  const float* Wq2 = (const float*)d_in[25];
  const float* Wk2 = (const float*)d_in[26];
  const float* Wv2 = (const float*)d_in[27];
  const float* Wq3 = (const float*)d_in[28];
  const float* Wk3 = (const float*)d_in[29];
  const float* Wv3 = (const float*)d_in[30];
  const float* Wf = (const float*)d_in[31];
  const float* bf = (const float*)d_in[32];
  float* out = (float*)d_out;

  const int B = NB, N0 = 4096, N1 = 512, N2 = 128, N3 = 64;
  char* base = (char*)d_ws;
  size_t off = 0;
  auto alloc = [&](size_t bytes) -> void* {
    void* p = base + off;
    off += (bytes + 255) & ~(size_t)255;
    return p;
  };
  float4* xw0 = (float4*)alloc((size_t)B * N0 * 16);
  float4* xw1 = (float4*)alloc((size_t)B * N1 * 16);
  float4* xw2 = (float4*)alloc((size_t)B * N2 * 16);
  float4* xw3 = (float4*)alloc((size_t)B * N3 * 16);
  int* idxK0 = (int*)alloc((size_t)B * N0 * 16 * 4);
  int* idxK1 = (int*)alloc((size_t)B * N1 * 16 * 4);
  int* idxK2 = (int*)alloc((size_t)B * N2 * 16 * 4);
  int* idxK3 = (int*)alloc((size_t)B * N3 * 16 * 4);
  int* idx1 = (int*)alloc((size_t)B * N1 * 4);
  int* idx2 = (int*)alloc((size_t)B * N2 * 4);
  int* idx3 = (int*)alloc((size_t)B * N3 * 4);
  float* fea0 = (float*)alloc((size_t)B * N0 * 64 * 4);
  float* fea1 = (float*)alloc((size_t)B * N1 * 128 * 4);
  float* fea1b = (float*)alloc((size_t)B * N1 * 256 * 4);
  float* fea2a = (float*)alloc((size_t)B * N2 * 256 * 4);
  float* fea2b = (float*)alloc((size_t)B * N2 * 256 * 4);
  float* fea2c = (float*)alloc((size_t)B * N2 * 256 * 4);
  float* fea2d = (float*)alloc((size_t)B * N2 * 256 * 4);
  float* fea3a = (float*)alloc((size_t)B * N3 * 512 * 4);
  float* fea3b = (float*)alloc((size_t)B * N3 * 512 * 4);
  float* qb = (float*)alloc((size_t)B * 32768 * 4);
  float* kb = (float*)alloc((size_t)B * 32768 * 4);
  float* vb = (float*)alloc((size_t)B * 32768 * 4);
  int* idxI2 = (int*)alloc((size_t)B * N2 * 3 * 4);
  float* wI2 = (float*)alloc((size_t)B * N2 * 3 * 4);
  int* idxI1 = (int*)alloc((size_t)B * N1 * 3 * 4);
  float* wI1 = (float*)alloc((size_t)B * N1 * 3 * 4);
  int* idxI0 = (int*)alloc((size_t)B * N0 * 3 * 4);
  float* wI0 = (float*)alloc((size_t)B * N0 * 3 * 4);
  float* Zb4 = (float*)alloc((size_t)B * N3 * 256 * 4);
  float* Zb5 = (float*)alloc((size_t)B * N2 * 256 * 4);
  float* Zb6 = (float*)alloc((size_t)B * N1 * 128 * 4);
  float* Y4 = (float*)alloc((size_t)B * N2 * 256 * 4);
  float* Y5 = (float*)alloc((size_t)B * N1 * 256 * 4);
  float* Y6 = (float*)alloc((size_t)B * N0 * 128 * 4);
  float* wfb = (float*)alloc((size_t)B * N0 * 320 * 4);

  float r2_0 = (float)(0.06 * 0.06);
  float r2_1 = (float)(0.12 * 0.12);
  float r2_2 = (float)(0.3 * 0.3);
  float r2_3 = (float)(0.5 * 0.5);

  // 0: pack coords + norms
  norms_kernel<<<B * N0 / 256, 256, 0, stream>>>(xyz, xw0, B * N0);

  // A: fps(4096->512) || L0 knn+gw+gemm
  combo_A_kernel<<<B + B * N0 / 4, 256, 0, stream>>>(xw0, r2_0, idxK0, W[0], bi[0], A[0],
                                                     fea0, idx1, xw1);
  // B: fps(512->128) || L1 knn+gw || interp0 || Y6a = fea0@W6a
  combo_B_kernel<<<NB + 512 + 64 + 1024, 256, 0, stream>>>(
      xw0, xw1, r2_1, idxK1, idx1, fea0, A[1], wfb, idx2, xw2, idxI0, wI0, W[6], Y6);
  // C: gemm L1 -> fea1
  gemm_kernel<<<dim3(2, B * N1 / 32), 256, 0, stream>>>(wfb, W[1], bi[1], fea1, 64, 128, 1);
  // D: fps(128->64) || L2 knn+gw || interp1 || Y5a = fea1@W5a
  combo_D_kernel<<<NB + 128 + 8 + 256, 256, 0, stream>>>(
      xw1, xw2, r2_2, idxK2, idx2, fea1, A[2], wfb, idx3, xw3, idxI1, wI1, W[5], Y5);
  // E: gemm L2 -> fea2a; qkv1; attn1 -> fea2b
  gemm_kernel<<<dim3(4, B * N2 / 32), 256, 0, stream>>>(wfb, W[2], bi[2], fea2a, 128, 256, 1);
  gemm_qkv_kernel<<<dim3(4, B * N2 / 32, 3), 256, 0, stream>>>(fea2a, Wq1, Wk1, Wv1, qb, kb,
                                                               vb, 256, 256);
  attn_kernel<<<dim3(N2, B), 128, 0, stream>>>(qb, kb, vb, fea2a, fea2b, N2, 256);

  // H: L3 knn+gw || interp2 || Y4a = fea2b@W4a
  combo_H_kernel<<<64 + 2 + 64, 256, 0, stream>>>(xw2, xw3, r2_3, idxK3, idx3, fea2b, A[3],
                                                  wfb, idxI2, wI2, W[4], Y4);
  // I: gemm L3 -> fea3a; qkv2; attn2 -> fea3b
  gemm_kernel<<<dim3(8, B * N3 / 32), 256, 0, stream>>>(wfb, W[3], bi[3], fea3a, 256, 512, 1);
  gemm_qkv_kernel<<<dim3(8, B * N3 / 32, 3), 256, 0, stream>>>(fea3a, Wq2, Wk2, Wv2, qb, kb,
                                                               vb, 512, 512);
  attn_kernel<<<dim3(N3, B), 128, 0, stream>>>(qb, kb, vb, fea3a, fea3b, N3, 512);

  // L4: Zb4 = fea3b@W4b; Y4 += interp(Zb4); gwpost -> fea2c; qkv3; attn3
  gemm_kernel<<<dim3(4, B * N3 / 32), 256, 0, stream>>>(fea3b, W[4] + 256 * 256, nullptr, Zb4,
                                                        512, 256, 0);
  interp_add_kernel<<<B * N2 * 256 / 256, 256, 0, stream>>>(Y4, idxI2, wI2, Zb4, N2, N3, 256,
                                                            B * N2 * 256);
  gwpost_kernel<<<B * N2, 64, 0, stream>>>(xw2, Y4, idxK2, A[4], bi[4], fea2c, N2, 256);
  gemm_qkv_kernel<<<dim3(4, B * N2 / 32, 3), 256, 0, stream>>>(fea2c, Wq3, Wk3, Wv3, qb, kb,
                                                               vb, 256, 256);
  attn_kernel<<<dim3(N2, B), 128, 0, stream>>>(qb, kb, vb, fea2c, fea2d, N2, 256);

  // L5: Zb5 = fea2d@W5b; Y5 += interp(Zb5); gwpost -> fea1b
  gemm_kernel<<<dim3(4, B * N2 / 32), 256, 0, stream>>>(fea2d, W[5] + 128 * 256, nullptr, Zb5,
                                                        256, 256, 0);
  interp_add_kernel<<<B * N1 * 256 / 256, 256, 0, stream>>>(Y5, idxI1, wI1, Zb5, N1, N2, 256,
                                                            B * N1 * 256);
  gwpost_kernel<<<B * N1, 64, 0, stream>>>(xw1, Y5, idxK1, A[5], bi[5], fea1b, N1, 256);

  // L6: Zb6 = fea1b@W6b; Y6 += interp(Zb6); gwpost+final -> out
  gemm_kernel<<<dim3(2, B * N1 / 32), 256, 0, stream>>>(fea1b, W[6] + 64 * 128, nullptr, Zb6,
                                                        256, 128, 0);
  interp_add_kernel<<<B * N0 * 128 / 256, 256, 0, stream>>>(Y6, idxI0, wI0, Zb6, N0, N1, 128,
                                                            B * N0 * 128);
  gwpost_final_kernel<<<B * N0, 64, 0, stream>>>(xw0, Y6, idxK0, A[6], bi[6], Wf, bf, out,
                                                 N0);
}